// Round 5
// baseline (15809.283 us; speedup 1.0000x reference)
//
#include <hip/hip_runtime.h>
#include <stdint.h>
#include <math.h>

#define NW      4096
#define TSTEPS  5722     // BURNIN + (512-1)*11 + 1
#define BURN    100
#define SSTRIDE 11
#define CH      1024
#define NTHR    256      // init threads; main loop = first wave only

struct K2 { uint32_t a, b; };

// Threefry-2x32, 20 rounds — matches jax._src.prng.threefry2x32 exactly.
__device__ __forceinline__ K2 tf(uint32_t k0, uint32_t k1, uint32_t c0, uint32_t c1) {
  uint32_t ks2 = k0 ^ k1 ^ 0x1BD11BDAu;
  uint32_t x0 = c0 + k0, x1 = c1 + k1;
#define RR(r) { x0 += x1; x1 = (x1 << (r)) | (x1 >> (32 - (r))); x1 ^= x0; }
  RR(13) RR(15) RR(26) RR(6)
  x0 += k1;  x1 += ks2 + 1u;
  RR(17) RR(29) RR(16) RR(24)
  x0 += ks2; x1 += k0 + 2u;
  RR(13) RR(15) RR(26) RR(6)
  x0 += k0;  x1 += k1 + 3u;
  RR(17) RR(29) RR(16) RR(24)
  x0 += k1;  x1 += ks2 + 4u;
  RR(13) RR(15) RR(26) RR(6)
  x0 += ks2; x1 += k0 + 5u;
#undef RR
  K2 r; r.a = x0; r.b = x1; return r;
}

__device__ __forceinline__ uint32_t xbits(K2 k) {
  K2 r = tf(k.a, k.b, 0u, 0u);
  return r.a ^ r.b;
}

__device__ __forceinline__ uint32_t ri_off(K2 key, uint32_t span) {
  K2 k1 = tf(key.a, key.b, 0u, 0u);
  K2 k2 = tf(key.a, key.b, 0u, 1u);
  uint32_t hb = xbits(k1);
  uint32_t lb = xbits(k2);
  uint32_t m = 65536u % span;
  m = (m * m) % span;
  return ((hb % span) * m + (lb % span)) % span;
}

__device__ __forceinline__ void make_prop(uint32_t kca, uint32_t kcb, int t,
                                          uint32_t& lohi, uint32_t& shv, float& lg) {
  K2 kt = tf(kca, kcb, 0u, (uint32_t)t);
  K2 kl = tf(kt.a, kt.b, 0u, 0u);
  K2 ka = tf(kt.a, kt.b, 0u, 1u);
  K2 kr = tf(kt.a, kt.b, 0u, 2u);
  K2 ku = tf(kt.a, kt.b, 0u, 3u);
  uint32_t l = 1u + ri_off(kl, 4095u);
  uint32_t a = ri_off(ka, 4097u - l);
  uint32_t b = a + l;
  uint32_t r = ri_off(kr, 4096u - l);
  uint32_t c = (b + r + 1u) % 4097u;
  uint32_t lo, hi, sh;
  if (a < c) { lo = a; hi = c; sh = b - a; }
  else       { lo = c; hi = b; sh = a - c; }
  uint32_t ub = xbits(ku);
  float uf = __uint_as_float((ub >> 9) | 0x3F800000u) - 1.0f;
  lohi = lo | (hi << 16);
  shv  = sh;
  lg   = (float)log((double)uf);
}

// smap: post-rotation source map. hi = lo + span. One unsigned compare covers both bounds.
__device__ __forceinline__ uint32_t smap2(uint32_t i, uint32_t lo, uint32_t span, uint32_t sh) {
  uint32_t t = i - lo;              // wraps huge if i < lo
  uint32_t u = t + sh;
  u = (u >= span) ? u - span : u;   // valid only when t < span
  return (t < span) ? lo + u : i;
}

// grid-parallel proposal precompute -> d_ws (16B records)
__global__ void prop_kernel(uint4* __restrict__ gprop) {
  int t = blockIdx.x * 256 + threadIdx.x;
  if (t >= TSTEPS) return;
  K2 kchain = tf(0u, 42u, 0u, 1u);
  uint32_t lohi, shv; float lg;
  make_prop(kchain.a, kchain.b, t, lohi, shv, lg);
  gprop[t] = make_uint4(lohi, shv, __float_as_uint(lg), 0u);
}

__device__ __forceinline__ void issue6(float (&dst)[6],
    uint32_t Q0, uint32_t Q1, uint32_t Q2, uint32_t Q3, uint32_t Q4, uint32_t Q5,
    uint32_t lo2, uint32_t hi2,
    const float* __restrict__ bigram, const float* __restrict__ startw,
    const float* __restrict__ endw) {
  // pl=Q0, pls=Q1, pls1=Q2, ph1=Q3, pm1=Q4, ph=Q5
  dst[0] = bigram[(size_t)Q3 * NW + Q0];
  dst[1] = bigram[(size_t)Q2 * NW + Q1];
  dst[2] = (lo2 > 0u)           ? bigram[(size_t)Q4 * NW + Q1] : startw[Q1];
  dst[3] = (lo2 > 0u)           ? bigram[(size_t)Q4 * NW + Q0] : startw[Q0];
  dst[4] = (hi2 < (uint32_t)NW) ? bigram[(size_t)Q2 * NW + Q5] : endw[Q2];
  dst[5] = (hi2 < (uint32_t)NW) ? bigram[(size_t)Q3 * NW + Q5] : endw[Q3];
}

// Consumes VR/VA (loads issued 2 steps ago, same-parity buffer) and refills
// them in place with speculative loads for step T+2.
__device__ __forceinline__ void step_body(
    int T, int TT, uint32_t lane, bool& accp,
    uint32_t (&Plo)[4], uint32_t (&Phi)[4], uint32_t (&Psh)[4], float (&Plg)[4],
    float (&VR)[6], float (&VA)[6],
    uint32_t* s_perm, uint32_t* s_tmp,
    const uint32_t* s_plohi, const uint32_t* s_psh, const float* s_plg,
    const float* __restrict__ bigram, const float* __restrict__ startw,
    const float* __restrict__ endw, int* __restrict__ out) {

  // ---- positions from proposal t+2 (slot 2) ----
  uint32_t lo2 = Plo[2], hi2 = Phi[2], sh2 = Psh[2];
  uint32_t g0 = lo2, g1 = lo2 + sh2, g2 = g1 - 1u, g3 = hi2 - 1u;
  uint32_t g4 = (lo2 > 0u) ? lo2 - 1u : 0u;
  uint32_t g5 = (hi2 < (uint32_t)NW) ? hi2 : 0u;

  // ---- inner smap (proposal t+1, slot 1) ----
  uint32_t lo1 = Plo[1], sp1 = Phi[1] - Plo[1], sh1 = Psh[1];
  uint32_t y0 = smap2(g0, lo1, sp1, sh1), y1 = smap2(g1, lo1, sp1, sh1);
  uint32_t y2 = smap2(g2, lo1, sp1, sh1), y3 = smap2(g3, lo1, sp1, sh1);
  uint32_t y4 = smap2(g4, lo1, sp1, sh1), y5 = smap2(g5, lo1, sp1, sh1);

  // ---- outer smap (proposal t, slot 0) — both acc_t variants ----
  uint32_t lo0 = Plo[0], sp0 = Phi[0] - Plo[0], sh0 = Psh[0];
  uint32_t zA0 = smap2(g0, lo0, sp0, sh0), zA1 = smap2(g1, lo0, sp0, sh0);
  uint32_t zA2 = smap2(g2, lo0, sp0, sh0), zA3 = smap2(g3, lo0, sp0, sh0);
  uint32_t zA4 = smap2(g4, lo0, sp0, sh0), zA5 = smap2(g5, lo0, sp0, sh0);
  uint32_t zB0 = smap2(y0, lo0, sp0, sh0), zB1 = smap2(y1, lo0, sp0, sh0);
  uint32_t zB2 = smap2(y2, lo0, sp0, sh0), zB3 = smap2(y3, lo0, sp0, sh0);
  uint32_t zB4 = smap2(y4, lo0, sp0, sh0), zB5 = smap2(y5, lo0, sp0, sh0);

  // ---- 24 LDS broadcast reads of P_t (pre-rotation state) ----
  uint32_t PR0 = s_perm[g0],  PR1 = s_perm[g1],  PR2 = s_perm[g2];
  uint32_t PR3 = s_perm[g3],  PR4 = s_perm[g4],  PR5 = s_perm[g5];
  uint32_t PB0 = s_perm[y0],  PB1 = s_perm[y1],  PB2 = s_perm[y2];
  uint32_t PB3 = s_perm[y3],  PB4 = s_perm[y4],  PB5 = s_perm[y5];
  uint32_t PA0 = s_perm[zA0], PA1 = s_perm[zA1], PA2 = s_perm[zA2];
  uint32_t PA3 = s_perm[zA3], PA4 = s_perm[zA4], PA5 = s_perm[zA5];
  uint32_t PC0 = s_perm[zB0], PC1 = s_perm[zB1], PC2 = s_perm[zB2];
  uint32_t PC3 = s_perm[zB3], PC4 = s_perm[zB4], PC5 = s_perm[zB5];

  // ---- prefetch proposal t+3 into slot 3 (uniform) ----
  {
    uint32_t lh = __builtin_amdgcn_readfirstlane(s_plohi[TT + 3]);
    Plo[3] = lh & 0xFFFFu; Phi[3] = lh >> 16;
    Psh[3] = __builtin_amdgcn_readfirstlane(s_psh[TT + 3]);
    Plg[3] = __uint_as_float(__builtin_amdgcn_readfirstlane(__float_as_uint(s_plg[TT + 3])));
  }

  // ---- decision t (vmcnt wait on 2-step-old loads lands here) ----
  float u0 = accp ? VA[0] : VR[0];
  float u1 = accp ? VA[1] : VR[1];
  float u2 = accp ? VA[2] : VR[2];
  float u3 = accp ? VA[3] : VR[3];
  float u4 = accp ? VA[4] : VR[4];
  float u5 = accp ? VA[5] : VR[5];
  double d = ((double)u0 - (double)u1) + ((double)u2 - (double)u3) + ((double)u4 - (double)u5);
  double mind = d < 0.0 ? d : 0.0;
  bool acc = mind > (double)Plg[0];
  int uacc = __builtin_amdgcn_readfirstlane((int)acc);

  // ---- select perm values, refill THIS buffer with loads for step t+2 ----
  uint32_t QR0 = uacc ? PA0 : PR0, QR1 = uacc ? PA1 : PR1, QR2 = uacc ? PA2 : PR2;
  uint32_t QR3 = uacc ? PA3 : PR3, QR4 = uacc ? PA4 : PR4, QR5 = uacc ? PA5 : PR5;
  uint32_t QA0 = uacc ? PC0 : PB0, QA1 = uacc ? PC1 : PB1, QA2 = uacc ? PC2 : PB2;
  uint32_t QA3 = uacc ? PC3 : PB3, QA4 = uacc ? PC4 : PB4, QA5 = uacc ? PC5 : PB5;
  issue6(VR, QR0, QR1, QR2, QR3, QR4, QR5, lo2, hi2, bigram, startw, endw);
  issue6(VA, QA0, QA1, QA2, QA3, QA4, QA5, lo2, hi2, bigram, startw, endw);

  // ---- rotation: LDS-staged two-phase copy (no register array, no scratch) ----
  if (uacc) {
    uint32_t n1 = sp0 - sh0;
    // phase 1a: tmp[0 .. n1) = perm[lo+sh .. hi)   (contiguous)
    for (uint32_t i = lane; i < n1; i += 64u)
      s_tmp[i] = s_perm[lo0 + sh0 + i];
    // phase 1b: tmp[n1 .. span) = perm[lo .. lo+sh)  (contiguous)
    for (uint32_t i = lane; i < sh0; i += 64u)
      s_tmp[n1 + i] = s_perm[lo0 + i];
    asm volatile("s_waitcnt lgkmcnt(0)" ::: "memory");
    __builtin_amdgcn_sched_barrier(0);
    // phase 2: perm[lo .. hi) = tmp[0 .. span)
    for (uint32_t i = lane; i < sp0; i += 64u)
      s_perm[lo0 + i] = s_tmp[i];
    asm volatile("s_waitcnt lgkmcnt(0)" ::: "memory");
    __builtin_amdgcn_sched_barrier(0);
  }

  // ---- emission (post-rotation state = perms[T]) ----
  if (T >= BURN && (T - BURN) % SSTRIDE == 0) {
    asm volatile("s_waitcnt lgkmcnt(0)" ::: "memory");
    __builtin_amdgcn_sched_barrier(0);
    int row = (T - BURN) / SSTRIDE;
    int* orow = out + (size_t)row * NW;
    #pragma unroll
    for (int k = 0; k < 16; ++k) {
      uint4 wv = *(const uint4*)&s_perm[k * 256 + (int)lane * 4];
      *(uint4*)&orow[k * 256 + (int)lane * 4] = wv;
    }
  }

  // ---- shift proposal slots ----
  Plo[0] = Plo[1]; Phi[0] = Phi[1]; Psh[0] = Psh[1]; Plg[0] = Plg[1];
  Plo[1] = Plo[2]; Phi[1] = Phi[2]; Psh[1] = Psh[2]; Plg[1] = Plg[2];
  Plo[2] = Plo[3]; Phi[2] = Phi[3]; Psh[2] = Psh[3]; Plg[2] = Plg[3];
  accp = acc;
}

__global__ __launch_bounds__(NTHR)
void TwoOptMCMC_86148454023515_kernel(const float* __restrict__ bigram,
                                      const float* __restrict__ startw,
                                      const float* __restrict__ endw,
                                      int* __restrict__ out,
                                      const uint4* __restrict__ gprop) {
  __shared__ __align__(16) uint32_t s_perm[NW + 4];
  __shared__ unsigned long long     s_comp[NW];       // init sort; tmp for rotation after
  __shared__ uint32_t               s_plohi[CH + 4];
  __shared__ uint32_t               s_psh[CH + 4];
  __shared__ float                  s_plg[CH + 4];

  uint32_t* s_tmp = (uint32_t*)s_comp;
  const int tid = threadIdx.x;
  K2 kinit  = tf(0u, 42u, 0u, 0u);
  K2 kchain = tf(0u, 42u, 0u, 1u);

  // ---- initial permutation: 2-round stable-sort shuffle (256 threads) ----
  for (int i = tid; i < NW; i += NTHR) s_perm[i] = (uint32_t)i;
  __syncthreads();
  K2 kc = kinit;
  for (int rnd = 0; rnd < 2; ++rnd) {
    K2 knext = tf(kc.a, kc.b, 0u, 0u);
    K2 ksub  = tf(kc.a, kc.b, 0u, 1u);
    for (int i = tid; i < NW; i += NTHR) {
      K2 r = tf(ksub.a, ksub.b, 0u, (uint32_t)i);
      uint32_t sk = r.a ^ r.b;
      s_comp[i] = ((unsigned long long)sk << 24) |
                  ((unsigned long long)(uint32_t)i << 12) |
                  (unsigned long long)s_perm[i];
    }
    __syncthreads();
    for (int k = 2; k <= NW; k <<= 1) {
      for (int j = k >> 1; j > 0; j >>= 1) {
        for (int i = tid; i < NW; i += NTHR) {
          int ixj = i ^ j;
          if (ixj > i) {
            unsigned long long va = s_comp[i], vb = s_comp[ixj];
            bool up = ((i & k) == 0);
            if ((va > vb) == up) { s_comp[i] = vb; s_comp[ixj] = va; }
          }
        }
        __syncthreads();
      }
    }
    for (int i = tid; i < NW; i += NTHR) s_perm[i] = (uint32_t)(s_comp[i] & 0xFFFull);
    __syncthreads();
    kc = knext;
  }

  if (tid >= 64) return;            // single wave from here on; no barriers below
  const uint32_t lane = (uint32_t)tid;

#define REFILL(T0) do { \
    for (int i = (int)lane; i < CH + 3; i += 64) { \
      int tq = (T0) + i; \
      uint32_t lohi, shv; float lg; \
      if (tq < TSTEPS) { \
        if (gprop) { uint4 rr = gprop[tq]; lohi = rr.x; shv = rr.y; lg = __uint_as_float(rr.z); } \
        else { make_prop(kchain.a, kchain.b, tq, lohi, shv, lg); } \
      } else { lohi = 0u | (2u << 16); shv = 1u; lg = 0.f; } \
      s_plohi[i] = lohi; s_psh[i] = shv; s_plg[i] = lg; \
    } \
    asm volatile("s_waitcnt lgkmcnt(0)" ::: "memory"); \
    __builtin_amdgcn_sched_barrier(0); \
  } while (0)

  REFILL(0);

  uint32_t Plo[4], Phi[4], Psh[4]; float Plg[4];
  #pragma unroll
  for (int s = 0; s < 3; ++s) {
    uint32_t lh = __builtin_amdgcn_readfirstlane(s_plohi[s]);
    Plo[s] = lh & 0xFFFFu; Phi[s] = lh >> 16;
    Psh[s] = __builtin_amdgcn_readfirstlane(s_psh[s]);
    Plg[s] = __uint_as_float(__builtin_amdgcn_readfirstlane(__float_as_uint(s_plg[s])));
  }
  Plo[3] = 0; Phi[3] = 2; Psh[3] = 1; Plg[3] = 0.f;

  float vR[6], vA[6], wR[6], wA[6];
  bool accp = false;

  // prologue: loads for t=0 (direct from P_0) -> vR/vA (consumed at step 0)
  {
    uint32_t lo2 = Plo[0], hi2 = Phi[0], sh2 = Psh[0];
    uint32_t g0 = lo2, g1 = lo2 + sh2, g2 = g1 - 1u, g3 = hi2 - 1u;
    uint32_t g4 = (lo2 > 0u) ? lo2 - 1u : 0u;
    uint32_t g5 = (hi2 < (uint32_t)NW) ? hi2 : 0u;
    uint32_t Q0 = s_perm[g0], Q1 = s_perm[g1], Q2 = s_perm[g2];
    uint32_t Q3 = s_perm[g3], Q4 = s_perm[g4], Q5 = s_perm[g5];
    issue6(vR, Q0, Q1, Q2, Q3, Q4, Q5, lo2, hi2, bigram, startw, endw);
    issue6(vA, Q0, Q1, Q2, Q3, Q4, Q5, lo2, hi2, bigram, startw, endw);
  }
  // prologue: loads for t=1 (both acc_0 variants) -> wR/wA (consumed at step 1)
  {
    uint32_t lo2 = Plo[1], hi2 = Phi[1], sh2 = Psh[1];
    uint32_t g0 = lo2, g1 = lo2 + sh2, g2 = g1 - 1u, g3 = hi2 - 1u;
    uint32_t g4 = (lo2 > 0u) ? lo2 - 1u : 0u;
    uint32_t g5 = (hi2 < (uint32_t)NW) ? hi2 : 0u;
    uint32_t lo0 = Plo[0], sp0 = Phi[0] - Plo[0], sh0 = Psh[0];
    uint32_t z0 = smap2(g0, lo0, sp0, sh0), z1 = smap2(g1, lo0, sp0, sh0);
    uint32_t z2 = smap2(g2, lo0, sp0, sh0), z3 = smap2(g3, lo0, sp0, sh0);
    uint32_t z4 = smap2(g4, lo0, sp0, sh0), z5 = smap2(g5, lo0, sp0, sh0);
    uint32_t QR0 = s_perm[g0], QR1 = s_perm[g1], QR2 = s_perm[g2];
    uint32_t QR3 = s_perm[g3], QR4 = s_perm[g4], QR5 = s_perm[g5];
    uint32_t QA0 = s_perm[z0], QA1 = s_perm[z1], QA2 = s_perm[z2];
    uint32_t QA3 = s_perm[z3], QA4 = s_perm[z4], QA5 = s_perm[z5];
    issue6(wR, QR0, QR1, QR2, QR3, QR4, QR5, lo2, hi2, bigram, startw, endw);
    issue6(wA, QA0, QA1, QA2, QA3, QA4, QA5, lo2, hi2, bigram, startw, endw);
  }

  for (int t0 = 0; t0 < TSTEPS; t0 += CH) {
    if (t0 > 0) REFILL(t0);
    int nch = (TSTEPS - t0 < CH) ? (TSTEPS - t0) : CH;  // always even here
    for (int tt = 0; tt < nch; tt += 2) {
      step_body(t0 + tt,     tt,     lane, accp, Plo, Phi, Psh, Plg,
                vR, vA, s_perm, s_tmp, s_plohi, s_psh, s_plg,
                bigram, startw, endw, out);
      step_body(t0 + tt + 1, tt + 1, lane, accp, Plo, Phi, Psh, Plg,
                wR, wA, s_perm, s_tmp, s_plohi, s_psh, s_plg,
                bigram, startw, endw, out);
    }
  }
#undef REFILL
}

extern "C" void kernel_launch(void* const* d_in, const int* in_sizes, int n_in,
                              void* d_out, int out_size, void* d_ws, size_t ws_size,
                              hipStream_t stream) {
  (void)in_sizes; (void)n_in; (void)out_size;
  const float* bigram = (const float*)d_in[1];
  const float* startw = (const float*)d_in[2];
  const float* endw   = (const float*)d_in[3];
  int* out = (int*)d_out;
  uint4* gprop = nullptr;
  if (ws_size >= (size_t)TSTEPS * 16) {
    gprop = (uint4*)d_ws;
    hipLaunchKernelGGL(prop_kernel, dim3((TSTEPS + 255) / 256), dim3(256), 0, stream, gprop);
  }
  hipLaunchKernelGGL(TwoOptMCMC_86148454023515_kernel, dim3(1), dim3(NTHR), 0, stream,
                     bigram, startw, endw, out, gprop);
}

// Round 6
// 9527.927 us; speedup vs baseline: 1.6593x; 1.6593x over previous
//
#include <hip/hip_runtime.h>
#include <stdint.h>
#include <math.h>

#define NW      4096
#define TSTEPS  5722     // BURNIN + (512-1)*11 + 1
#define BURN    100
#define SSTRIDE 11
#define CH      1024
#define NTHR    256      // 4 waves, all redundant in the front-end

struct K2 { uint32_t a, b; };

// Threefry-2x32, 20 rounds — matches jax._src.prng.threefry2x32 exactly.
__device__ __forceinline__ K2 tf(uint32_t k0, uint32_t k1, uint32_t c0, uint32_t c1) {
  uint32_t ks2 = k0 ^ k1 ^ 0x1BD11BDAu;
  uint32_t x0 = c0 + k0, x1 = c1 + k1;
#define RR(r) { x0 += x1; x1 = (x1 << (r)) | (x1 >> (32 - (r))); x1 ^= x0; }
  RR(13) RR(15) RR(26) RR(6)
  x0 += k1;  x1 += ks2 + 1u;
  RR(17) RR(29) RR(16) RR(24)
  x0 += ks2; x1 += k0 + 2u;
  RR(13) RR(15) RR(26) RR(6)
  x0 += k0;  x1 += k1 + 3u;
  RR(17) RR(29) RR(16) RR(24)
  x0 += k1;  x1 += ks2 + 4u;
  RR(13) RR(15) RR(26) RR(6)
  x0 += ks2; x1 += k0 + 5u;
#undef RR
  K2 r; r.a = x0; r.b = x1; return r;
}

__device__ __forceinline__ uint32_t xbits(K2 k) {
  K2 r = tf(k.a, k.b, 0u, 0u);
  return r.a ^ r.b;
}

__device__ __forceinline__ uint32_t ri_off(K2 key, uint32_t span) {
  K2 k1 = tf(key.a, key.b, 0u, 0u);
  K2 k2 = tf(key.a, key.b, 0u, 1u);
  uint32_t hb = xbits(k1);
  uint32_t lb = xbits(k2);
  uint32_t m = 65536u % span;
  m = (m * m) % span;
  return ((hb % span) * m + (lb % span)) % span;
}

__device__ __forceinline__ void make_prop(uint32_t kca, uint32_t kcb, int t,
                                          uint32_t& lohi, uint32_t& shv, float& lg) {
  K2 kt = tf(kca, kcb, 0u, (uint32_t)t);
  K2 kl = tf(kt.a, kt.b, 0u, 0u);
  K2 ka = tf(kt.a, kt.b, 0u, 1u);
  K2 kr = tf(kt.a, kt.b, 0u, 2u);
  K2 ku = tf(kt.a, kt.b, 0u, 3u);
  uint32_t l = 1u + ri_off(kl, 4095u);
  uint32_t a = ri_off(ka, 4097u - l);
  uint32_t b = a + l;
  uint32_t r = ri_off(kr, 4096u - l);
  uint32_t c = (b + r + 1u) % 4097u;
  uint32_t lo, hi, sh;
  if (a < c) { lo = a; hi = c; sh = b - a; }
  else       { lo = c; hi = b; sh = a - c; }
  uint32_t ub = xbits(ku);
  float uf = __uint_as_float((ub >> 9) | 0x3F800000u) - 1.0f;
  lohi = lo | (hi << 16);
  shv  = sh;
  lg   = (float)log((double)uf);
}

// smap: post-rotation source map. hi = lo + span. One unsigned compare covers both bounds.
__device__ __forceinline__ uint32_t smap2(uint32_t i, uint32_t lo, uint32_t span, uint32_t sh) {
  uint32_t t = i - lo;              // wraps huge if i < lo
  uint32_t u = t + sh;
  u = (u >= span) ? u - span : u;   // valid only when t < span
  return (t < span) ? lo + u : i;
}

// grid-parallel proposal precompute -> d_ws (16B records)
__global__ void prop_kernel(uint4* __restrict__ gprop) {
  int t = blockIdx.x * 256 + threadIdx.x;
  if (t >= TSTEPS) return;
  K2 kchain = tf(0u, 42u, 0u, 1u);
  uint32_t lohi, shv; float lg;
  make_prop(kchain.a, kchain.b, t, lohi, shv, lg);
  gprop[t] = make_uint4(lohi, shv, __float_as_uint(lg), 0u);
}

__device__ __forceinline__ void issue6(float (&dst)[6],
    uint32_t Q0, uint32_t Q1, uint32_t Q2, uint32_t Q3, uint32_t Q4, uint32_t Q5,
    uint32_t lo2, uint32_t hi2,
    const float* __restrict__ bigram, const float* __restrict__ startw,
    const float* __restrict__ endw) {
  // pl=Q0, pls=Q1, pls1=Q2, ph1=Q3, pm1=Q4, ph=Q5
  dst[0] = bigram[(size_t)Q3 * NW + Q0];
  dst[1] = bigram[(size_t)Q2 * NW + Q1];
  dst[2] = (lo2 > 0u)           ? bigram[(size_t)Q4 * NW + Q1] : startw[Q1];
  dst[3] = (lo2 > 0u)           ? bigram[(size_t)Q4 * NW + Q0] : startw[Q0];
  dst[4] = (hi2 < (uint32_t)NW) ? bigram[(size_t)Q2 * NW + Q5] : endw[Q2];
  dst[5] = (hi2 < (uint32_t)NW) ? bigram[(size_t)Q3 * NW + Q5] : endw[Q3];
}

// raw barrier: NO vmcnt drain (keeps speculative global loads in flight)
#define SYNC() do { asm volatile("s_waitcnt lgkmcnt(0)" ::: "memory"); \
                    __builtin_amdgcn_s_barrier(); } while (0)

// Consumes VR/VA (this wave's loads issued 2 steps ago, same-parity buffer)
// and refills them in place with speculative loads for step T+2.
// ALL 256 threads execute this redundantly; barriers only around rotation writes.
__device__ __forceinline__ void step_body(
    int T, int TT, int tid, bool& accp,
    uint32_t (&Plo)[4], uint32_t (&Phi)[4], uint32_t (&Psh)[4], float (&Plg)[4],
    float (&VR)[6], float (&VA)[6],
    uint32_t* s_perm, const uint32_t* s_plohi, const uint32_t* s_psh, const float* s_plg,
    const float* __restrict__ bigram, const float* __restrict__ startw,
    const float* __restrict__ endw, int* __restrict__ out) {

  // ---- positions from proposal t+2 (slot 2) ----
  uint32_t lo2 = Plo[2], hi2 = Phi[2], sh2 = Psh[2];
  uint32_t g0 = lo2, g1 = lo2 + sh2, g2 = g1 - 1u, g3 = hi2 - 1u;
  uint32_t g4 = (lo2 > 0u) ? lo2 - 1u : 0u;
  uint32_t g5 = (hi2 < (uint32_t)NW) ? hi2 : 0u;

  // ---- inner smap (proposal t+1, slot 1) ----
  uint32_t lo1 = Plo[1], sp1 = Phi[1] - Plo[1], sh1 = Psh[1];
  uint32_t y0 = smap2(g0, lo1, sp1, sh1), y1 = smap2(g1, lo1, sp1, sh1);
  uint32_t y2 = smap2(g2, lo1, sp1, sh1), y3 = smap2(g3, lo1, sp1, sh1);
  uint32_t y4 = smap2(g4, lo1, sp1, sh1), y5 = smap2(g5, lo1, sp1, sh1);

  // ---- outer smap (proposal t, slot 0) — both acc_t variants ----
  uint32_t lo0 = Plo[0], sp0 = Phi[0] - Plo[0], sh0 = Psh[0];
  uint32_t zA0 = smap2(g0, lo0, sp0, sh0), zA1 = smap2(g1, lo0, sp0, sh0);
  uint32_t zA2 = smap2(g2, lo0, sp0, sh0), zA3 = smap2(g3, lo0, sp0, sh0);
  uint32_t zA4 = smap2(g4, lo0, sp0, sh0), zA5 = smap2(g5, lo0, sp0, sh0);
  uint32_t zB0 = smap2(y0, lo0, sp0, sh0), zB1 = smap2(y1, lo0, sp0, sh0);
  uint32_t zB2 = smap2(y2, lo0, sp0, sh0), zB3 = smap2(y3, lo0, sp0, sh0);
  uint32_t zB4 = smap2(y4, lo0, sp0, sh0), zB5 = smap2(y5, lo0, sp0, sh0);

  // ---- 24 LDS broadcast reads of P_t (pre-rotation state) ----
  uint32_t PR0 = s_perm[g0],  PR1 = s_perm[g1],  PR2 = s_perm[g2];
  uint32_t PR3 = s_perm[g3],  PR4 = s_perm[g4],  PR5 = s_perm[g5];
  uint32_t PB0 = s_perm[y0],  PB1 = s_perm[y1],  PB2 = s_perm[y2];
  uint32_t PB3 = s_perm[y3],  PB4 = s_perm[y4],  PB5 = s_perm[y5];
  uint32_t PA0 = s_perm[zA0], PA1 = s_perm[zA1], PA2 = s_perm[zA2];
  uint32_t PA3 = s_perm[zA3], PA4 = s_perm[zA4], PA5 = s_perm[zA5];
  uint32_t PC0 = s_perm[zB0], PC1 = s_perm[zB1], PC2 = s_perm[zB2];
  uint32_t PC3 = s_perm[zB3], PC4 = s_perm[zB4], PC5 = s_perm[zB5];

  // ---- prefetch proposal t+3 into slot 3 (uniform per wave) ----
  {
    uint32_t lh = __builtin_amdgcn_readfirstlane(s_plohi[TT + 3]);
    Plo[3] = lh & 0xFFFFu; Phi[3] = lh >> 16;
    Psh[3] = __builtin_amdgcn_readfirstlane(s_psh[TT + 3]);
    Plg[3] = __uint_as_float(__builtin_amdgcn_readfirstlane(__float_as_uint(s_plg[TT + 3])));
  }

  // ---- decision t (vmcnt wait on this wave's 2-step-old loads) ----
  float u0 = accp ? VA[0] : VR[0];
  float u1 = accp ? VA[1] : VR[1];
  float u2 = accp ? VA[2] : VR[2];
  float u3 = accp ? VA[3] : VR[3];
  float u4 = accp ? VA[4] : VR[4];
  float u5 = accp ? VA[5] : VR[5];
  double d = ((double)u0 - (double)u1) + ((double)u2 - (double)u3) + ((double)u4 - (double)u5);
  double mind = d < 0.0 ? d : 0.0;
  bool acc = mind > (double)Plg[0];
  int uacc = __builtin_amdgcn_readfirstlane((int)acc);

  // ---- select perm values, refill THIS buffer with loads for step t+2 ----
  uint32_t QR0 = uacc ? PA0 : PR0, QR1 = uacc ? PA1 : PR1, QR2 = uacc ? PA2 : PR2;
  uint32_t QR3 = uacc ? PA3 : PR3, QR4 = uacc ? PA4 : PR4, QR5 = uacc ? PA5 : PR5;
  uint32_t QA0 = uacc ? PC0 : PB0, QA1 = uacc ? PC1 : PB1, QA2 = uacc ? PC2 : PB2;
  uint32_t QA3 = uacc ? PC3 : PB3, QA4 = uacc ? PC4 : PB4, QA5 = uacc ? PC5 : PB5;
  issue6(VR, QR0, QR1, QR2, QR3, QR4, QR5, lo2, hi2, bigram, startw, endw);
  issue6(VA, QA0, QA1, QA2, QA3, QA4, QA5, lo2, hi2, bigram, startw, endw);

  // ---- rotation: 256 threads, 16-deep register staging (R2's proven form) ----
  if (uacc) {
    uint32_t rv[16];
    #pragma unroll
    for (int k = 0; k < 16; ++k) {
      uint32_t i = (uint32_t)tid + (uint32_t)k * 256u;
      if (i < sp0) {
        uint32_t s = i + sh0; if (s >= sp0) s -= sp0;
        rv[k] = s_perm[lo0 + s];
      }
    }
    SYNC();   // all reads done (lgkmcnt only; speculative vmcnt stays in flight)
    #pragma unroll
    for (int k = 0; k < 16; ++k) {
      uint32_t i = (uint32_t)tid + (uint32_t)k * 256u;
      if (i < sp0) s_perm[lo0 + i] = rv[k];
    }
    SYNC();   // writes visible before any wave's next reads
  }

  // ---- emission (post-rotation state = perms[T]), 4-way split ----
  if (T >= BURN && (T - BURN) % SSTRIDE == 0) {
    int row = (T - BURN) / SSTRIDE;
    int* orow = out + (size_t)row * NW;
    #pragma unroll
    for (int k = 0; k < 4; ++k) {
      int i = (k * NTHR + tid) * 4;
      uint4 wv = *(const uint4*)&s_perm[i];
      *(uint4*)&orow[i] = wv;
    }
  }

  // ---- shift proposal slots ----
  Plo[0] = Plo[1]; Phi[0] = Phi[1]; Psh[0] = Psh[1]; Plg[0] = Plg[1];
  Plo[1] = Plo[2]; Phi[1] = Phi[2]; Psh[1] = Psh[2]; Plg[1] = Plg[2];
  Plo[2] = Plo[3]; Phi[2] = Phi[3]; Psh[2] = Psh[3]; Plg[2] = Plg[3];
  accp = acc;
}

__global__ __launch_bounds__(NTHR)
void TwoOptMCMC_86148454023515_kernel(const float* __restrict__ bigram,
                                      const float* __restrict__ startw,
                                      const float* __restrict__ endw,
                                      int* __restrict__ out,
                                      const uint4* __restrict__ gprop) {
  __shared__ __align__(16) uint32_t s_perm[NW + 4];
  __shared__ unsigned long long     s_comp[NW];       // init sort only
  __shared__ uint32_t               s_plohi[CH + 4];
  __shared__ uint32_t               s_psh[CH + 4];
  __shared__ float                  s_plg[CH + 4];

  const int tid = threadIdx.x;
  K2 kinit  = tf(0u, 42u, 0u, 0u);
  K2 kchain = tf(0u, 42u, 0u, 1u);

  // ---- initial permutation: 2-round stable-sort shuffle (256 threads) ----
  for (int i = tid; i < NW; i += NTHR) s_perm[i] = (uint32_t)i;
  __syncthreads();
  K2 kc = kinit;
  for (int rnd = 0; rnd < 2; ++rnd) {
    K2 knext = tf(kc.a, kc.b, 0u, 0u);
    K2 ksub  = tf(kc.a, kc.b, 0u, 1u);
    for (int i = tid; i < NW; i += NTHR) {
      K2 r = tf(ksub.a, ksub.b, 0u, (uint32_t)i);
      uint32_t sk = r.a ^ r.b;
      s_comp[i] = ((unsigned long long)sk << 24) |
                  ((unsigned long long)(uint32_t)i << 12) |
                  (unsigned long long)s_perm[i];
    }
    __syncthreads();
    for (int k = 2; k <= NW; k <<= 1) {
      for (int j = k >> 1; j > 0; j >>= 1) {
        for (int i = tid; i < NW; i += NTHR) {
          int ixj = i ^ j;
          if (ixj > i) {
            unsigned long long va = s_comp[i], vb = s_comp[ixj];
            bool up = ((i & k) == 0);
            if ((va > vb) == up) { s_comp[i] = vb; s_comp[ixj] = va; }
          }
        }
        __syncthreads();
      }
    }
    for (int i = tid; i < NW; i += NTHR) s_perm[i] = (uint32_t)(s_comp[i] & 0xFFFull);
    __syncthreads();
    kc = knext;
  }

  // ---- all 4 waves run the chain redundantly; barriers only around writes ----

#define REFILL(T0) do { \
    SYNC();  /* all waves done consuming previous chunk's slots */ \
    for (int i = tid; i < CH + 3; i += NTHR) { \
      int tq = (T0) + i; \
      uint32_t lohi, shv; float lg; \
      if (tq < TSTEPS) { \
        if (gprop) { uint4 rr = gprop[tq]; lohi = rr.x; shv = rr.y; lg = __uint_as_float(rr.z); } \
        else { make_prop(kchain.a, kchain.b, tq, lohi, shv, lg); } \
      } else { lohi = 0u | (2u << 16); shv = 1u; lg = 0.f; } \
      s_plohi[i] = lohi; s_psh[i] = shv; s_plg[i] = lg; \
    } \
    SYNC();  /* publish */ \
  } while (0)

  REFILL(0);

  uint32_t Plo[4], Phi[4], Psh[4]; float Plg[4];
  #pragma unroll
  for (int s = 0; s < 3; ++s) {
    uint32_t lh = __builtin_amdgcn_readfirstlane(s_plohi[s]);
    Plo[s] = lh & 0xFFFFu; Phi[s] = lh >> 16;
    Psh[s] = __builtin_amdgcn_readfirstlane(s_psh[s]);
    Plg[s] = __uint_as_float(__builtin_amdgcn_readfirstlane(__float_as_uint(s_plg[s])));
  }
  Plo[3] = 0; Phi[3] = 2; Psh[3] = 1; Plg[3] = 0.f;

  float vR[6], vA[6], wR[6], wA[6];
  bool accp = false;

  // prologue: loads for t=0 (direct from P_0) -> vR/vA (consumed at step 0)
  {
    uint32_t lo2 = Plo[0], hi2 = Phi[0], sh2 = Psh[0];
    uint32_t g0 = lo2, g1 = lo2 + sh2, g2 = g1 - 1u, g3 = hi2 - 1u;
    uint32_t g4 = (lo2 > 0u) ? lo2 - 1u : 0u;
    uint32_t g5 = (hi2 < (uint32_t)NW) ? hi2 : 0u;
    uint32_t Q0 = s_perm[g0], Q1 = s_perm[g1], Q2 = s_perm[g2];
    uint32_t Q3 = s_perm[g3], Q4 = s_perm[g4], Q5 = s_perm[g5];
    issue6(vR, Q0, Q1, Q2, Q3, Q4, Q5, lo2, hi2, bigram, startw, endw);
    issue6(vA, Q0, Q1, Q2, Q3, Q4, Q5, lo2, hi2, bigram, startw, endw);
  }
  // prologue: loads for t=1 (both acc_0 variants) -> wR/wA (consumed at step 1)
  {
    uint32_t lo2 = Plo[1], hi2 = Phi[1], sh2 = Psh[1];
    uint32_t g0 = lo2, g1 = lo2 + sh2, g2 = g1 - 1u, g3 = hi2 - 1u;
    uint32_t g4 = (lo2 > 0u) ? lo2 - 1u : 0u;
    uint32_t g5 = (hi2 < (uint32_t)NW) ? hi2 : 0u;
    uint32_t lo0 = Plo[0], sp0 = Phi[0] - Plo[0], sh0 = Psh[0];
    uint32_t z0 = smap2(g0, lo0, sp0, sh0), z1 = smap2(g1, lo0, sp0, sh0);
    uint32_t z2 = smap2(g2, lo0, sp0, sh0), z3 = smap2(g3, lo0, sp0, sh0);
    uint32_t z4 = smap2(g4, lo0, sp0, sh0), z5 = smap2(g5, lo0, sp0, sh0);
    uint32_t QR0 = s_perm[g0], QR1 = s_perm[g1], QR2 = s_perm[g2];
    uint32_t QR3 = s_perm[g3], QR4 = s_perm[g4], QR5 = s_perm[g5];
    uint32_t QA0 = s_perm[z0], QA1 = s_perm[z1], QA2 = s_perm[z2];
    uint32_t QA3 = s_perm[z3], QA4 = s_perm[z4], QA5 = s_perm[z5];
    issue6(wR, QR0, QR1, QR2, QR3, QR4, QR5, lo2, hi2, bigram, startw, endw);
    issue6(wA, QA0, QA1, QA2, QA3, QA4, QA5, lo2, hi2, bigram, startw, endw);
  }

  for (int t0 = 0; t0 < TSTEPS; t0 += CH) {
    if (t0 > 0) REFILL(t0);
    int nch = (TSTEPS - t0 < CH) ? (TSTEPS - t0) : CH;  // always even here
    for (int tt = 0; tt < nch; tt += 2) {
      step_body(t0 + tt,     tt,     tid, accp, Plo, Phi, Psh, Plg,
                vR, vA, s_perm, s_plohi, s_psh, s_plg,
                bigram, startw, endw, out);
      step_body(t0 + tt + 1, tt + 1, tid, accp, Plo, Phi, Psh, Plg,
                wR, wA, s_perm, s_plohi, s_psh, s_plg,
                bigram, startw, endw, out);
    }
  }
#undef REFILL
}

extern "C" void kernel_launch(void* const* d_in, const int* in_sizes, int n_in,
                              void* d_out, int out_size, void* d_ws, size_t ws_size,
                              hipStream_t stream) {
  (void)in_sizes; (void)n_in; (void)out_size;
  const float* bigram = (const float*)d_in[1];
  const float* startw = (const float*)d_in[2];
  const float* endw   = (const float*)d_in[3];
  int* out = (int*)d_out;
  uint4* gprop = nullptr;
  if (ws_size >= (size_t)TSTEPS * 16) {
    gprop = (uint4*)d_ws;
    hipLaunchKernelGGL(prop_kernel, dim3((TSTEPS + 255) / 256), dim3(256), 0, stream, gprop);
  }
  hipLaunchKernelGGL(TwoOptMCMC_86148454023515_kernel, dim3(1), dim3(NTHR), 0, stream,
                     bigram, startw, endw, out, gprop);
}

// Round 7
// 7820.763 us; speedup vs baseline: 2.0215x; 1.2183x over previous
//
#include <hip/hip_runtime.h>
#include <stdint.h>
#include <math.h>

#define NW      4096
#define TSTEPS  5722     // BURNIN + (512-1)*11 + 1
#define BURN    100
#define SSTRIDE 11
#define CH      1024
#define NTHR    256      // wave 0 = front-end; all 4 waves rotate/emit

struct K2 { uint32_t a, b; };

// Threefry-2x32, 20 rounds — matches jax._src.prng.threefry2x32 exactly.
__device__ __forceinline__ K2 tf(uint32_t k0, uint32_t k1, uint32_t c0, uint32_t c1) {
  uint32_t ks2 = k0 ^ k1 ^ 0x1BD11BDAu;
  uint32_t x0 = c0 + k0, x1 = c1 + k1;
#define RR(r) { x0 += x1; x1 = (x1 << (r)) | (x1 >> (32 - (r))); x1 ^= x0; }
  RR(13) RR(15) RR(26) RR(6)
  x0 += k1;  x1 += ks2 + 1u;
  RR(17) RR(29) RR(16) RR(24)
  x0 += ks2; x1 += k0 + 2u;
  RR(13) RR(15) RR(26) RR(6)
  x0 += k0;  x1 += k1 + 3u;
  RR(17) RR(29) RR(16) RR(24)
  x0 += k1;  x1 += ks2 + 4u;
  RR(13) RR(15) RR(26) RR(6)
  x0 += ks2; x1 += k0 + 5u;
#undef RR
  K2 r; r.a = x0; r.b = x1; return r;
}

__device__ __forceinline__ uint32_t xbits(K2 k) {
  K2 r = tf(k.a, k.b, 0u, 0u);
  return r.a ^ r.b;
}

__device__ __forceinline__ uint32_t ri_off(K2 key, uint32_t span) {
  K2 k1 = tf(key.a, key.b, 0u, 0u);
  K2 k2 = tf(key.a, key.b, 0u, 1u);
  uint32_t hb = xbits(k1);
  uint32_t lb = xbits(k2);
  uint32_t m = 65536u % span;
  m = (m * m) % span;
  return ((hb % span) * m + (lb % span)) % span;
}

__device__ __forceinline__ void make_prop(uint32_t kca, uint32_t kcb, int t,
                                          uint32_t& lohi, uint32_t& shv, float& lg) {
  K2 kt = tf(kca, kcb, 0u, (uint32_t)t);
  K2 kl = tf(kt.a, kt.b, 0u, 0u);
  K2 ka = tf(kt.a, kt.b, 0u, 1u);
  K2 kr = tf(kt.a, kt.b, 0u, 2u);
  K2 ku = tf(kt.a, kt.b, 0u, 3u);
  uint32_t l = 1u + ri_off(kl, 4095u);
  uint32_t a = ri_off(ka, 4097u - l);
  uint32_t b = a + l;
  uint32_t r = ri_off(kr, 4096u - l);
  uint32_t c = (b + r + 1u) % 4097u;
  uint32_t lo, hi, sh;
  if (a < c) { lo = a; hi = c; sh = b - a; }
  else       { lo = c; hi = b; sh = a - c; }
  uint32_t ub = xbits(ku);
  float uf = __uint_as_float((ub >> 9) | 0x3F800000u) - 1.0f;
  lohi = lo | (hi << 16);
  shv  = sh;
  lg   = (float)log((double)uf);
}

// smap: post-rotation source map. One unsigned compare covers both bounds.
__device__ __forceinline__ uint32_t smap2(uint32_t i, uint32_t lo, uint32_t span, uint32_t sh) {
  uint32_t t = i - lo;              // wraps huge if i < lo
  uint32_t u = t + sh;
  u = (u >= span) ? u - span : u;   // valid only when t < span
  return (t < span) ? lo + u : i;
}

// grid-parallel proposal precompute -> d_ws (16B records)
__global__ void prop_kernel(uint4* __restrict__ gprop) {
  int t = blockIdx.x * 256 + threadIdx.x;
  if (t >= TSTEPS) return;
  K2 kchain = tf(0u, 42u, 0u, 1u);
  uint32_t lohi, shv; float lg;
  make_prop(kchain.a, kchain.b, t, lohi, shv, lg);
  gprop[t] = make_uint4(lohi, shv, __float_as_uint(lg), 0u);
}

__device__ __forceinline__ void issue6(float (&dst)[6],
    uint32_t Q0, uint32_t Q1, uint32_t Q2, uint32_t Q3, uint32_t Q4, uint32_t Q5,
    uint32_t lo2, uint32_t hi2,
    const float* __restrict__ bigram, const float* __restrict__ startw,
    const float* __restrict__ endw) {
  // pl=Q0, pls=Q1, pls1=Q2, ph1=Q3, pm1=Q4, ph=Q5
  dst[0] = bigram[(size_t)Q3 * NW + Q0];
  dst[1] = bigram[(size_t)Q2 * NW + Q1];
  dst[2] = (lo2 > 0u)           ? bigram[(size_t)Q4 * NW + Q1] : startw[Q1];
  dst[3] = (lo2 > 0u)           ? bigram[(size_t)Q4 * NW + Q0] : startw[Q0];
  dst[4] = (hi2 < (uint32_t)NW) ? bigram[(size_t)Q2 * NW + Q5] : endw[Q2];
  dst[5] = (hi2 < (uint32_t)NW) ? bigram[(size_t)Q3 * NW + Q5] : endw[Q3];
}

// raw barrier: NO vmcnt drain (keeps speculative global loads in flight)
#define SYNC() do { asm volatile("s_waitcnt lgkmcnt(0)" ::: "memory"); \
                    __builtin_amdgcn_s_barrier(); } while (0)

// tid0 front-end: consumes VR/VA (loads issued 2 steps ago, same-parity
// buffer), refills them in place for step T+2, publishes decision via s_bc.
// Waves 1-3 skip straight to the barrier, then rotate/emit.
__device__ __forceinline__ void step_body(
    int T, int TT, int tid, bool& accp,
    uint32_t (&Plo)[4], uint32_t (&Phi)[4], uint32_t (&Psh)[4], float (&Plg)[4],
    float (&VR)[6], float (&VA)[6],
    uint32_t* s_perm, uint32_t* s_bc,
    const uint32_t* s_plohi, const uint32_t* s_psh, const float* s_plg,
    const float* __restrict__ bigram, const float* __restrict__ startw,
    const float* __restrict__ endw, int* __restrict__ out) {

  if (tid == 0) {
    // ---- positions from proposal t+2 (slot 2) ----
    uint32_t lo2 = Plo[2], hi2 = Phi[2], sh2 = Psh[2];
    uint32_t g0 = lo2, g1 = lo2 + sh2, g2 = g1 - 1u, g3 = hi2 - 1u;
    uint32_t g4 = (lo2 > 0u) ? lo2 - 1u : 0u;
    uint32_t g5 = (hi2 < (uint32_t)NW) ? hi2 : 0u;

    // ---- inner smap (proposal t+1, slot 1) ----
    uint32_t lo1 = Plo[1], sp1 = Phi[1] - Plo[1], sh1 = Psh[1];
    uint32_t y0 = smap2(g0, lo1, sp1, sh1), y1 = smap2(g1, lo1, sp1, sh1);
    uint32_t y2 = smap2(g2, lo1, sp1, sh1), y3 = smap2(g3, lo1, sp1, sh1);
    uint32_t y4 = smap2(g4, lo1, sp1, sh1), y5 = smap2(g5, lo1, sp1, sh1);

    // ---- outer smap (proposal t, slot 0) — both acc_t variants ----
    uint32_t lo0 = Plo[0], sp0 = Phi[0] - Plo[0], sh0 = Psh[0];
    uint32_t zA0 = smap2(g0, lo0, sp0, sh0), zA1 = smap2(g1, lo0, sp0, sh0);
    uint32_t zA2 = smap2(g2, lo0, sp0, sh0), zA3 = smap2(g3, lo0, sp0, sh0);
    uint32_t zA4 = smap2(g4, lo0, sp0, sh0), zA5 = smap2(g5, lo0, sp0, sh0);
    uint32_t zB0 = smap2(y0, lo0, sp0, sh0), zB1 = smap2(y1, lo0, sp0, sh0);
    uint32_t zB2 = smap2(y2, lo0, sp0, sh0), zB3 = smap2(y3, lo0, sp0, sh0);
    uint32_t zB4 = smap2(y4, lo0, sp0, sh0), zB5 = smap2(y5, lo0, sp0, sh0);

    // ---- 24 LDS reads of P_t (pre-rotation state) ----
    uint32_t PR0 = s_perm[g0],  PR1 = s_perm[g1],  PR2 = s_perm[g2];
    uint32_t PR3 = s_perm[g3],  PR4 = s_perm[g4],  PR5 = s_perm[g5];
    uint32_t PB0 = s_perm[y0],  PB1 = s_perm[y1],  PB2 = s_perm[y2];
    uint32_t PB3 = s_perm[y3],  PB4 = s_perm[y4],  PB5 = s_perm[y5];
    uint32_t PA0 = s_perm[zA0], PA1 = s_perm[zA1], PA2 = s_perm[zA2];
    uint32_t PA3 = s_perm[zA3], PA4 = s_perm[zA4], PA5 = s_perm[zA5];
    uint32_t PC0 = s_perm[zB0], PC1 = s_perm[zB1], PC2 = s_perm[zB2];
    uint32_t PC3 = s_perm[zB3], PC4 = s_perm[zB4], PC5 = s_perm[zB5];

    // ---- prefetch proposal t+3 into slot 3 ----
    uint32_t lh3 = s_plohi[TT + 3];
    uint32_t sh3 = s_psh[TT + 3];
    float    lg3 = s_plg[TT + 3];

    // ---- decision t (vmcnt wait on 2-step-old loads lands here) ----
    float u0 = accp ? VA[0] : VR[0];
    float u1 = accp ? VA[1] : VR[1];
    float u2 = accp ? VA[2] : VR[2];
    float u3 = accp ? VA[3] : VR[3];
    float u4 = accp ? VA[4] : VR[4];
    float u5 = accp ? VA[5] : VR[5];
    double d = ((double)u0 - (double)u1) + ((double)u2 - (double)u3) + ((double)u4 - (double)u5);
    double mind = d < 0.0 ? d : 0.0;
    bool acc = mind > (double)Plg[0];

    // ---- publish decision + rotation params for the other waves ----
    uint32_t* bc = s_bc + (T & 1) * 4;
    bc[0] = acc ? 1u : 0u;
    bc[1] = lo0; bc[2] = Phi[0]; bc[3] = sh0;

    // ---- select perm values, refill THIS buffer with loads for t+2 ----
    uint32_t QR0 = acc ? PA0 : PR0, QR1 = acc ? PA1 : PR1, QR2 = acc ? PA2 : PR2;
    uint32_t QR3 = acc ? PA3 : PR3, QR4 = acc ? PA4 : PR4, QR5 = acc ? PA5 : PR5;
    uint32_t QA0 = acc ? PC0 : PB0, QA1 = acc ? PC1 : PB1, QA2 = acc ? PC2 : PB2;
    uint32_t QA3 = acc ? PC3 : PB3, QA4 = acc ? PC4 : PB4, QA5 = acc ? PC5 : PB5;
    issue6(VR, QR0, QR1, QR2, QR3, QR4, QR5, lo2, hi2, bigram, startw, endw);
    issue6(VA, QA0, QA1, QA2, QA3, QA4, QA5, lo2, hi2, bigram, startw, endw);

    // ---- shift proposal slots ----
    Plo[0] = Plo[1]; Phi[0] = Phi[1]; Psh[0] = Psh[1]; Plg[0] = Plg[1];
    Plo[1] = Plo[2]; Phi[1] = Phi[2]; Psh[1] = Psh[2]; Plg[1] = Plg[2];
    Plo[2] = lh3 & 0xFFFFu; Phi[2] = lh3 >> 16; Psh[2] = sh3; Plg[2] = lg3;
    accp = acc;
  }

  SYNC();   // release decision (lgkmcnt only; speculative vmcnt stays in flight)

  const uint32_t* bc = s_bc + (T & 1) * 4;
  uint32_t acc = bc[0];
  if (acc) {
    uint32_t lo = bc[1], hi = bc[2], sh = bc[3];
    uint32_t sp = hi - lo;
    uint32_t rv[16];
    #pragma unroll
    for (int k = 0; k < 16; ++k) {
      uint32_t i = (uint32_t)tid + (uint32_t)k * 256u;
      if (i < sp) {
        uint32_t s = i + sh; if (s >= sp) s -= sp;
        rv[k] = s_perm[lo + s];
      }
    }
    SYNC();   // all reads done
    #pragma unroll
    for (int k = 0; k < 16; ++k) {
      uint32_t i = (uint32_t)tid + (uint32_t)k * 256u;
      if (i < sp) s_perm[lo + i] = rv[k];
    }
    SYNC();   // writes visible before next step's reads
  }

  // ---- emission (post-rotation state = perms[T]), all 4 waves ----
  if (T >= BURN && (T - BURN) % SSTRIDE == 0) {
    int row = (T - BURN) / SSTRIDE;
    int* orow = out + (size_t)row * NW;
    #pragma unroll
    for (int k = 0; k < 4; ++k) {
      int i = (k * NTHR + tid) * 4;
      uint4 wv = *(const uint4*)&s_perm[i];
      *(uint4*)&orow[i] = wv;
    }
  }
}

__global__ __launch_bounds__(NTHR)
void TwoOptMCMC_86148454023515_kernel(const float* __restrict__ bigram,
                                      const float* __restrict__ startw,
                                      const float* __restrict__ endw,
                                      int* __restrict__ out,
                                      const uint4* __restrict__ gprop) {
  __shared__ __align__(16) uint32_t s_perm[NW + 4];
  __shared__ unsigned long long     s_comp[NW];       // init sort only
  __shared__ uint32_t               s_plohi[CH + 4];
  __shared__ uint32_t               s_psh[CH + 4];
  __shared__ float                  s_plg[CH + 4];
  __shared__ uint32_t               s_bc[8];          // double-buffered decision

  const int tid = threadIdx.x;
  K2 kinit  = tf(0u, 42u, 0u, 0u);
  K2 kchain = tf(0u, 42u, 0u, 1u);

  // ---- initial permutation: 2-round stable-sort shuffle (256 threads) ----
  for (int i = tid; i < NW; i += NTHR) s_perm[i] = (uint32_t)i;
  __syncthreads();
  K2 kc = kinit;
  for (int rnd = 0; rnd < 2; ++rnd) {
    K2 knext = tf(kc.a, kc.b, 0u, 0u);
    K2 ksub  = tf(kc.a, kc.b, 0u, 1u);
    for (int i = tid; i < NW; i += NTHR) {
      K2 r = tf(ksub.a, ksub.b, 0u, (uint32_t)i);
      uint32_t sk = r.a ^ r.b;
      s_comp[i] = ((unsigned long long)sk << 24) |
                  ((unsigned long long)(uint32_t)i << 12) |
                  (unsigned long long)s_perm[i];
    }
    __syncthreads();
    for (int k = 2; k <= NW; k <<= 1) {
      for (int j = k >> 1; j > 0; j >>= 1) {
        for (int i = tid; i < NW; i += NTHR) {
          int ixj = i ^ j;
          if (ixj > i) {
            unsigned long long va = s_comp[i], vb = s_comp[ixj];
            bool up = ((i & k) == 0);
            if ((va > vb) == up) { s_comp[i] = vb; s_comp[ixj] = va; }
          }
        }
        __syncthreads();
      }
    }
    for (int i = tid; i < NW; i += NTHR) s_perm[i] = (uint32_t)(s_comp[i] & 0xFFFull);
    __syncthreads();
    kc = knext;
  }

#define REFILL(T0) do { \
    SYNC();  /* all waves done with previous chunk's slots */ \
    for (int i = tid; i < CH + 3; i += NTHR) { \
      int tq = (T0) + i; \
      uint32_t lohi, shv; float lg; \
      if (tq < TSTEPS) { \
        if (gprop) { uint4 rr = gprop[tq]; lohi = rr.x; shv = rr.y; lg = __uint_as_float(rr.z); } \
        else { make_prop(kchain.a, kchain.b, tq, lohi, shv, lg); } \
      } else { lohi = 0u | (2u << 16); shv = 1u; lg = 0.f; } \
      s_plohi[i] = lohi; s_psh[i] = shv; s_plg[i] = lg; \
    } \
    SYNC();  /* publish */ \
  } while (0)

  REFILL(0);

  uint32_t Plo[4], Phi[4], Psh[4]; float Plg[4];
  #pragma unroll
  for (int s = 0; s < 3; ++s) {
    uint32_t lh = s_plohi[s];
    Plo[s] = lh & 0xFFFFu; Phi[s] = lh >> 16;
    Psh[s] = s_psh[s];
    Plg[s] = s_plg[s];
  }
  Plo[3] = 0; Phi[3] = 2; Psh[3] = 1; Plg[3] = 0.f;

  float vR[6], vA[6], wR[6], wA[6];
  bool accp = false;

  // prologue: loads for t=0 (direct from P_0) -> vR/vA (consumed at step 0)
  {
    uint32_t lo2 = Plo[0], hi2 = Phi[0], sh2 = Psh[0];
    uint32_t g0 = lo2, g1 = lo2 + sh2, g2 = g1 - 1u, g3 = hi2 - 1u;
    uint32_t g4 = (lo2 > 0u) ? lo2 - 1u : 0u;
    uint32_t g5 = (hi2 < (uint32_t)NW) ? hi2 : 0u;
    uint32_t Q0 = s_perm[g0], Q1 = s_perm[g1], Q2 = s_perm[g2];
    uint32_t Q3 = s_perm[g3], Q4 = s_perm[g4], Q5 = s_perm[g5];
    issue6(vR, Q0, Q1, Q2, Q3, Q4, Q5, lo2, hi2, bigram, startw, endw);
    issue6(vA, Q0, Q1, Q2, Q3, Q4, Q5, lo2, hi2, bigram, startw, endw);
  }
  // prologue: loads for t=1 (both acc_0 variants) -> wR/wA (consumed at step 1)
  {
    uint32_t lo2 = Plo[1], hi2 = Phi[1], sh2 = Psh[1];
    uint32_t g0 = lo2, g1 = lo2 + sh2, g2 = g1 - 1u, g3 = hi2 - 1u;
    uint32_t g4 = (lo2 > 0u) ? lo2 - 1u : 0u;
    uint32_t g5 = (hi2 < (uint32_t)NW) ? hi2 : 0u;
    uint32_t lo0 = Plo[0], sp0 = Phi[0] - Plo[0], sh0 = Psh[0];
    uint32_t z0 = smap2(g0, lo0, sp0, sh0), z1 = smap2(g1, lo0, sp0, sh0);
    uint32_t z2 = smap2(g2, lo0, sp0, sh0), z3 = smap2(g3, lo0, sp0, sh0);
    uint32_t z4 = smap2(g4, lo0, sp0, sh0), z5 = smap2(g5, lo0, sp0, sh0);
    uint32_t QR0 = s_perm[g0], QR1 = s_perm[g1], QR2 = s_perm[g2];
    uint32_t QR3 = s_perm[g3], QR4 = s_perm[g4], QR5 = s_perm[g5];
    uint32_t QA0 = s_perm[z0], QA1 = s_perm[z1], QA2 = s_perm[z2];
    uint32_t QA3 = s_perm[z3], QA4 = s_perm[z4], QA5 = s_perm[z5];
    issue6(wR, QR0, QR1, QR2, QR3, QR4, QR5, lo2, hi2, bigram, startw, endw);
    issue6(wA, QA0, QA1, QA2, QA3, QA4, QA5, lo2, hi2, bigram, startw, endw);
  }

  for (int t0 = 0; t0 < TSTEPS; t0 += CH) {
    if (t0 > 0) REFILL(t0);
    int nch = (TSTEPS - t0 < CH) ? (TSTEPS - t0) : CH;  // always even here
    for (int tt = 0; tt < nch; tt += 2) {
      step_body(t0 + tt,     tt,     tid, accp, Plo, Phi, Psh, Plg,
                vR, vA, s_perm, s_bc, s_plohi, s_psh, s_plg,
                bigram, startw, endw, out);
      step_body(t0 + tt + 1, tt + 1, tid, accp, Plo, Phi, Psh, Plg,
                wR, wA, s_perm, s_bc, s_plohi, s_psh, s_plg,
                bigram, startw, endw, out);
    }
  }
#undef REFILL
}

extern "C" void kernel_launch(void* const* d_in, const int* in_sizes, int n_in,
                              void* d_out, int out_size, void* d_ws, size_t ws_size,
                              hipStream_t stream) {
  (void)in_sizes; (void)n_in; (void)out_size;
  const float* bigram = (const float*)d_in[1];
  const float* startw = (const float*)d_in[2];
  const float* endw   = (const float*)d_in[3];
  int* out = (int*)d_out;
  uint4* gprop = nullptr;
  if (ws_size >= (size_t)TSTEPS * 16) {
    gprop = (uint4*)d_ws;
    hipLaunchKernelGGL(prop_kernel, dim3((TSTEPS + 255) / 256), dim3(256), 0, stream, gprop);
  }
  hipLaunchKernelGGL(TwoOptMCMC_86148454023515_kernel, dim3(1), dim3(NTHR), 0, stream,
                     bigram, startw, endw, out, gprop);
}

// Round 8
// 7379.252 us; speedup vs baseline: 2.1424x; 1.0598x over previous
//
#include <hip/hip_runtime.h>
#include <stdint.h>
#include <math.h>

#define NW      4096
#define TSTEPS  5722     // BURNIN + (512-1)*11 + 1
#define BURN    100
#define SSTRIDE 11
#define NTHR    256
#define NBOUND  522      // 10 burn-in windows(10) + window(1 @t=100) + 511 windows(11)

struct K2 { uint32_t a, b; };

// Threefry-2x32, 20 rounds — matches jax._src.prng.threefry2x32 exactly.
__device__ __forceinline__ K2 tf(uint32_t k0, uint32_t k1, uint32_t c0, uint32_t c1) {
  uint32_t ks2 = k0 ^ k1 ^ 0x1BD11BDAu;
  uint32_t x0 = c0 + k0, x1 = c1 + k1;
#define RR(r) { x0 += x1; x1 = (x1 << (r)) | (x1 >> (32 - (r))); x1 ^= x0; }
  RR(13) RR(15) RR(26) RR(6)
  x0 += k1;  x1 += ks2 + 1u;
  RR(17) RR(29) RR(16) RR(24)
  x0 += ks2; x1 += k0 + 2u;
  RR(13) RR(15) RR(26) RR(6)
  x0 += k0;  x1 += k1 + 3u;
  RR(17) RR(29) RR(16) RR(24)
  x0 += k1;  x1 += ks2 + 4u;
  RR(13) RR(15) RR(26) RR(6)
  x0 += ks2; x1 += k0 + 5u;
#undef RR
  K2 r; r.a = x0; r.b = x1; return r;
}

__device__ __forceinline__ uint32_t xbits(K2 k) {
  K2 r = tf(k.a, k.b, 0u, 0u);
  return r.a ^ r.b;
}

__device__ __forceinline__ uint32_t ri_off(K2 key, uint32_t span) {
  K2 k1 = tf(key.a, key.b, 0u, 0u);
  K2 k2 = tf(key.a, key.b, 0u, 1u);
  uint32_t hb = xbits(k1);
  uint32_t lb = xbits(k2);
  uint32_t m = 65536u % span;
  m = (m * m) % span;
  return ((hb % span) * m + (lb % span)) % span;
}

__device__ __noinline__ void make_prop(uint32_t kca, uint32_t kcb, int t,
                                       uint32_t& lohi, uint32_t& shv, float& lg) {
  K2 kt = tf(kca, kcb, 0u, (uint32_t)t);
  K2 kl = tf(kt.a, kt.b, 0u, 0u);
  K2 ka = tf(kt.a, kt.b, 0u, 1u);
  K2 kr = tf(kt.a, kt.b, 0u, 2u);
  K2 ku = tf(kt.a, kt.b, 0u, 3u);
  uint32_t l = 1u + ri_off(kl, 4095u);
  uint32_t a = ri_off(ka, 4097u - l);
  uint32_t b = a + l;
  uint32_t r = ri_off(kr, 4096u - l);
  uint32_t c = (b + r + 1u) % 4097u;
  uint32_t lo, hi, sh;
  if (a < c) { lo = a; hi = c; sh = b - a; }
  else       { lo = c; hi = b; sh = a - c; }
  uint32_t ub = xbits(ku);
  float uf = __uint_as_float((ub >> 9) | 0x3F800000u) - 1.0f;
  lohi = lo | (hi << 16);
  shv  = sh;
  lg   = (float)log((double)uf);
}

// smap: post-rotation source map (span = hi-lo).
__device__ __forceinline__ uint32_t smap2(uint32_t i, uint32_t lo, uint32_t span, uint32_t sh) {
  uint32_t t = i - lo;              // wraps huge if i < lo
  uint32_t u = t + sh;
  u = (u >= span) ? u - span : u;   // valid only when t < span
  return (t < span) ? lo + u : i;
}

// grid-parallel proposal precompute -> d_ws (16B records)
__global__ void prop_kernel(uint4* __restrict__ gprop) {
  int t = blockIdx.x * 256 + threadIdx.x;
  if (t >= TSTEPS) return;
  K2 kchain = tf(0u, 42u, 0u, 1u);
  uint32_t lohi, shv; float lg;
  make_prop(kchain.a, kchain.b, t, lohi, shv, lg);
  gprop[t] = make_uint4(lohi, shv, __float_as_uint(lg), 0u);
}

// raw barrier: NO vmcnt drain (keeps speculative global loads in flight)
#define SYNC() do { asm volatile("s_waitcnt lgkmcnt(0)" ::: "memory"); \
                    __builtin_amdgcn_s_barrier(); } while (0)

// compose through accepted-move stack, newest (highest index < jc) first.
// jc must be wave-uniform (scalar) so guards are scalar branches.
__device__ __forceinline__ uint32_t compose(uint32_t pos, int jc,
                                            const uint32_t (&mlh)[12],
                                            const uint32_t (&msh)[12]) {
  #pragma unroll
  for (int k = 11; k >= 0; --k)
    if (k < jc) pos = smap2(pos, mlh[k] & 0xFFFFu, mlh[k] >> 16, msh[k]);
  return pos;
}

// materialize new base = old base ∘ stack; optionally emit row.
__device__ __forceinline__ void mat_emit(int tid, int jcu, uint32_t cur,
                                         const uint32_t (&mlh)[12],
                                         const uint32_t (&msh)[12],
                                         uint32_t (*s_base)[NW],
                                         bool emit, int row, int* __restrict__ out) {
  uint32_t vals[16];
  #pragma unroll
  for (int k = 0; k < 16; ++k) {
    uint32_t i = (uint32_t)tid + (uint32_t)k * 256u;
    uint32_t pos = compose(i, jcu, mlh, msh);
    vals[k] = s_base[cur][pos];
  }
  #pragma unroll
  for (int k = 0; k < 16; ++k) {
    uint32_t i = (uint32_t)tid + (uint32_t)k * 256u;
    s_base[cur ^ 1u][i] = vals[k];
    if (emit) out[(size_t)row * NW + i] = (int)vals[k];
  }
}

// one MCMC step on wave 0, all lanes cooperating. Consumes ld (loads issued
// at T-2), refills it with speculative loads for T+2. Barrier-free.
__device__ __forceinline__ void stepf(
    int T, uint32_t lane, float& ld, bool& accp, int& jc,
    uint32_t (&mlh)[12], uint32_t (&msh)[12],
    uint32_t& s0lh, uint32_t& s0sh, float& s0lg,
    uint32_t& s1lh, uint32_t& s1sh, float& s1lg,
    uint32_t& s2lh, uint32_t& s2sh, float& s2lg,
    uint32_t& s3lh, uint32_t& s3sh, float& s3lg,
    const uint32_t* __restrict__ sbase,
    uint32_t* __restrict__ s_mvlh, uint32_t* __restrict__ s_mvsh,
    const float* __restrict__ bigram, const float* __restrict__ startw,
    const float* __restrict__ endw, const uint4* __restrict__ gprop,
    uint32_t kca, uint32_t kcb) {

  uint32_t p    = lane & 7u;
  uint32_t vset = (lane >> 3) & 3u;   // 0=R 1=B(S_{T+1}) 2=A(S_T) 3=C(S_T∘S_{T+1})

  // positions g from proposal T+2 (slot 2)
  uint32_t lo2 = s2lh & 0xFFFFu, hi2 = s2lh >> 16, sh2 = s2sh;
  uint32_t g0 = lo2, g1 = lo2 + sh2, g2v = g1 - 1u, g3 = hi2 - 1u;
  uint32_t g4 = (lo2 > 0u) ? lo2 - 1u : 0u;
  uint32_t g5 = (hi2 < (uint32_t)NW) ? hi2 : 0u;
  uint32_t pos = (p == 0u) ? g0 : (p == 1u) ? g1 : (p == 2u) ? g2v
               : (p == 3u) ? g3 : (p == 4u) ? g4 : g5;

  uint32_t lo1 = s1lh & 0xFFFFu, sp1 = (s1lh >> 16) - lo1, sh1 = s1sh;
  uint32_t lo0 = s0lh & 0xFFFFu, sp0 = (s0lh >> 16) - lo0, sh0 = s0sh;
  if (vset & 1u) pos = smap2(pos, lo1, sp1, sh1);
  if (vset & 2u) pos = smap2(pos, lo0, sp0, sh0);
  pos = compose(pos, jc, mlh, msh);
  uint32_t val = sbase[pos];                    // one ds_read, 32 lanes

  // prefetch proposal T+4 (slot3 holds T+3 at entry)
  int tq = T + 4; if (tq > TSTEPS - 1) tq = TSTEPS - 1;
  uint32_t nlh, nsh; float nlg;
  if (gprop) { uint4 gp = gprop[tq]; nlh = gp.x; nsh = gp.y; nlg = __uint_as_float(gp.z); }
  else       { make_prop(kca, kcb, tq, nlh, nsh, nlg); }

  // ---- decision for T (consumes 2-step-old loads via shfl) ----
  float uval = __shfl(ld, (int)((accp ? 8u : 0u) + p), 64);
  double du = (double)uval;
  if (p & 1u) du = -du;
  if (p >= 6u) du = 0.0;
  du += __shfl_xor(du, 1, 64);
  du += __shfl_xor(du, 2, 64);
  du += __shfl_xor(du, 4, 64);
  double dmin = du < 0.0 ? du : 0.0;
  int accl = (dmin > (double)s0lg) ? 1 : 0;     // valid lanes 0..7
  int acc = __builtin_amdgcn_readfirstlane(accl);   // scalar, uniform

  // ---- select Q values, issue 12 loads for T+2 (lanes 0-5, 8-13) ----
  uint32_t qv = (uint32_t)__shfl((int)val, (int)((uint32_t)acc * 16u + lane), 64);
  uint32_t base8 = lane & ~7u;
  uint32_t rsrc = (p == 0u) ? 3u : (p == 1u) ? 2u : (p <= 3u) ? 4u : (p == 4u) ? 2u : 3u;
  uint32_t csrc = (p == 0u) ? 0u : (p <= 2u) ? 1u : (p == 3u) ? 0u : 5u;
  uint32_t row = (uint32_t)__shfl((int)qv, (int)(base8 + rsrc), 64);
  uint32_t col = (uint32_t)__shfl((int)qv, (int)(base8 + csrc), 64);
  bool isbi = (p < 2u) || ((p < 4u) ? (lo2 > 0u) : (hi2 < (uint32_t)NW));
  const float* addr = isbi ? (bigram + (size_t)row * NW + col)
                           : ((p < 4u) ? (startw + col) : (endw + row));
  bool isload = (vset < 2u) && (p < 6u);
  if (isload) ld = *addr;

  // ---- bookkeeping (acc is scalar => uniform branches) ----
  if (acc) {
    #pragma unroll
    for (int k = 0; k < 12; ++k)
      if (k == jc) { mlh[k] = lo0 | (sp0 << 16); msh[k] = sh0; }
    if (lane == 0u) { s_mvlh[jc] = lo0 | (sp0 << 16); s_mvsh[jc] = sh0; }
    jc++;
  }
  accp = (acc != 0);

  // shift proposal slots
  s0lh = s1lh; s0sh = s1sh; s0lg = s1lg;
  s1lh = s2lh; s1sh = s2sh; s1lg = s2lg;
  s2lh = s3lh; s2sh = s3sh; s2lg = s3lg;
  s3lh = nlh;  s3sh = nsh;  s3lg = nlg;
}

__global__ __launch_bounds__(NTHR)
void TwoOptMCMC_86148454023515_kernel(const float* __restrict__ bigram,
                                      const float* __restrict__ startw,
                                      const float* __restrict__ endw,
                                      int* __restrict__ out,
                                      const uint4* __restrict__ gprop) {
  __shared__ __align__(16) uint32_t s_base[2][NW];   // 32 KB, ping-pong; aliased as u64 sort buf
  __shared__ uint32_t s_mvlh[12];
  __shared__ uint32_t s_mvsh[12];
  __shared__ uint32_t s_jc[1];

  unsigned long long* s_comp = (unsigned long long*)s_base;
  const int tid = threadIdx.x;
  K2 kinit  = tf(0u, 42u, 0u, 0u);
  K2 kchain = tf(0u, 42u, 0u, 1u);

  // ---- initial permutation: 2-round stable-sort shuffle ----
  // round composites: key<<24 | pos<<12 | perm. Round 1 perm = identity.
  {
    K2 kc = kinit;
    for (int rnd = 0; rnd < 2; ++rnd) {
      K2 knext = tf(kc.a, kc.b, 0u, 0u);
      K2 ksub  = tf(kc.a, kc.b, 0u, 1u);
      for (int i = tid; i < NW; i += NTHR) {
        K2 r = tf(ksub.a, ksub.b, 0u, (uint32_t)i);
        uint32_t sk = r.a ^ r.b;
        unsigned long long pv = (rnd == 0) ? (unsigned long long)(uint32_t)i
                                           : (s_comp[i] & 0xFFFull);
        s_comp[i] = ((unsigned long long)sk << 24) |
                    ((unsigned long long)(uint32_t)i << 12) | pv;
      }
      __syncthreads();
      for (int k = 2; k <= NW; k <<= 1) {
        for (int j = k >> 1; j > 0; j >>= 1) {
          for (int i = tid; i < NW; i += NTHR) {
            int ixj = i ^ j;
            if (ixj > i) {
              unsigned long long va = s_comp[i], vb = s_comp[ixj];
              bool up = ((i & k) == 0);
              if ((va > vb) == up) { s_comp[i] = vb; s_comp[ixj] = va; }
            }
          }
          __syncthreads();
        }
      }
      kc = knext;
    }
    // extract perm into s_base[0] (aliases s_comp: stage via registers)
    uint32_t pv[16];
    #pragma unroll
    for (int k = 0; k < 16; ++k) pv[k] = (uint32_t)(s_comp[tid + k * 256] & 0xFFFull);
    __syncthreads();
    #pragma unroll
    for (int k = 0; k < 16; ++k) s_base[0][tid + k * 256] = pv[k];
    __syncthreads();
  }

  const int wave = tid >> 6;
  const uint32_t lane = (uint32_t)(tid & 63);

  if (wave == 0) {
    // ---- wave 0: barrier-free MCMC windows ----
    uint32_t mlh[12], msh[12];
    #pragma unroll
    for (int k = 0; k < 12; ++k) { mlh[k] = 0u; msh[k] = 0u; }
    int jc = 0; bool accp = false; uint32_t cur = 0u;
    float ldA = 0.f, ldB = 0.f;

    // slots = proposals 0..3
    uint32_t s0lh, s0sh, s1lh, s1sh, s2lh, s2sh, s3lh, s3sh;
    float s0lg, s1lg, s2lg, s3lg;
    {
      uint32_t lh[4], sh[4]; float lg[4];
      #pragma unroll
      for (int j = 0; j < 4; ++j) {
        int tq = j; if (tq > TSTEPS - 1) tq = TSTEPS - 1;
        if (gprop) { uint4 gp = gprop[tq]; lh[j] = gp.x; sh[j] = gp.y; lg[j] = __uint_as_float(gp.z); }
        else       { make_prop(kchain.a, kchain.b, tq, lh[j], sh[j], lg[j]); }
      }
      s0lh = lh[0]; s0sh = sh[0]; s0lg = lg[0];
      s1lh = lh[1]; s1sh = sh[1]; s1lg = lg[1];
      s2lh = lh[2]; s2sh = sh[2]; s2lg = lg[2];
      s3lh = lh[3]; s3sh = sh[3]; s3lg = lg[3];
    }

    uint32_t p = lane & 7u;
    uint32_t vset = (lane >> 3) & 3u;
    uint32_t rsrc = (p == 0u) ? 3u : (p == 1u) ? 2u : (p <= 3u) ? 4u : (p == 4u) ? 2u : 3u;
    uint32_t csrc = (p == 0u) ? 0u : (p <= 2u) ? 1u : (p == 3u) ? 0u : 5u;
    bool isload = (vset < 2u) && (p < 6u);
    uint32_t base8 = lane & ~7u;

    // prologue A: loads for t=0, direct from P_0 (both sets identical)
    {
      uint32_t lo2 = s0lh & 0xFFFFu, hi2 = s0lh >> 16, sh2 = s0sh;
      uint32_t g0 = lo2, g1 = lo2 + sh2, g2v = g1 - 1u, g3 = hi2 - 1u;
      uint32_t g4 = (lo2 > 0u) ? lo2 - 1u : 0u;
      uint32_t g5 = (hi2 < (uint32_t)NW) ? hi2 : 0u;
      uint32_t pos = (p == 0u) ? g0 : (p == 1u) ? g1 : (p == 2u) ? g2v
                   : (p == 3u) ? g3 : (p == 4u) ? g4 : g5;
      uint32_t val = s_base[0][pos];
      uint32_t row = (uint32_t)__shfl((int)val, (int)(base8 + rsrc), 64);
      uint32_t col = (uint32_t)__shfl((int)val, (int)(base8 + csrc), 64);
      bool isbi = (p < 2u) || ((p < 4u) ? (lo2 > 0u) : (hi2 < (uint32_t)NW));
      const float* addr = isbi ? (bigram + (size_t)row * NW + col)
                               : ((p < 4u) ? (startw + col) : (endw + row));
      if (isload) ldA = *addr;
    }
    // prologue B: loads for t=1; set1 composes S_0
    {
      uint32_t lo2 = s1lh & 0xFFFFu, hi2 = s1lh >> 16, sh2 = s1sh;
      uint32_t g0 = lo2, g1 = lo2 + sh2, g2v = g1 - 1u, g3 = hi2 - 1u;
      uint32_t g4 = (lo2 > 0u) ? lo2 - 1u : 0u;
      uint32_t g5 = (hi2 < (uint32_t)NW) ? hi2 : 0u;
      uint32_t pos = (p == 0u) ? g0 : (p == 1u) ? g1 : (p == 2u) ? g2v
                   : (p == 3u) ? g3 : (p == 4u) ? g4 : g5;
      uint32_t lo0 = s0lh & 0xFFFFu, sp0 = (s0lh >> 16) - lo0, sh0 = s0sh;
      if (vset & 1u) pos = smap2(pos, lo0, sp0, sh0);
      uint32_t val = s_base[0][pos];
      uint32_t row = (uint32_t)__shfl((int)val, (int)(base8 + rsrc), 64);
      uint32_t col = (uint32_t)__shfl((int)val, (int)(base8 + csrc), 64);
      bool isbi = (p < 2u) || ((p < 4u) ? (lo2 > 0u) : (hi2 < (uint32_t)NW));
      const float* addr = isbi ? (bigram + (size_t)row * NW + col)
                               : ((p < 4u) ? (startw + col) : (endw + row));
      if (isload) ldB = *addr;
    }

    int t = 0;
    for (int b = 0; b < NBOUND; ++b) {
      int wlen = (b < 10) ? 10 : ((b == 10) ? 1 : 11);
      const uint32_t* sb = s_base[cur];
      #pragma unroll
      for (int k = 0; k < 11; ++k) {
        if (k < wlen) {
          if ((k & 1) == 0)
            stepf(t + k, lane, ldA, accp, jc, mlh, msh,
                  s0lh, s0sh, s0lg, s1lh, s1sh, s1lg, s2lh, s2sh, s2lg,
                  s3lh, s3sh, s3lg, sb, s_mvlh, s_mvsh,
                  bigram, startw, endw, gprop, kchain.a, kchain.b);
          else
            stepf(t + k, lane, ldB, accp, jc, mlh, msh,
                  s0lh, s0sh, s0lg, s1lh, s1sh, s1lg, s2lh, s2sh, s2lg,
                  s3lh, s3sh, s3lg, sb, s_mvlh, s_mvsh,
                  bigram, startw, endw, gprop, kchain.a, kchain.b);
        }
      }
      if (lane == 0u) s_jc[0] = (uint32_t)jc;
      SYNC();                                       // publish move list
      mat_emit(tid, jc, cur, mlh, msh, s_base, b >= 10, b - 10, out);
      SYNC();                                       // new base complete
      if (wlen & 1) { float tmp = ldA; ldA = ldB; ldB = tmp; }  // loads long done
      jc = 0; cur ^= 1u; t += wlen;
    }
  } else {
    // ---- waves 1-3: parked; materialize + emit at each boundary ----
    for (int b = 0; b < NBOUND; ++b) {
      SYNC();
      uint32_t mlh[12], msh[12];
      #pragma unroll
      for (int k = 0; k < 12; ++k) { mlh[k] = s_mvlh[k]; msh[k] = s_mvsh[k]; }
      int jcu = __builtin_amdgcn_readfirstlane((int)s_jc[0]);
      mat_emit(tid, jcu, (uint32_t)(b & 1), mlh, msh, s_base, b >= 10, b - 10, out);
      SYNC();
    }
  }
}

extern "C" void kernel_launch(void* const* d_in, const int* in_sizes, int n_in,
                              void* d_out, int out_size, void* d_ws, size_t ws_size,
                              hipStream_t stream) {
  (void)in_sizes; (void)n_in; (void)out_size;
  const float* bigram = (const float*)d_in[1];
  const float* startw = (const float*)d_in[2];
  const float* endw   = (const float*)d_in[3];
  int* out = (int*)d_out;
  uint4* gprop = nullptr;
  if (ws_size >= (size_t)TSTEPS * 16) {
    gprop = (uint4*)d_ws;
    hipLaunchKernelGGL(prop_kernel, dim3((TSTEPS + 255) / 256), dim3(256), 0, stream, gprop);
  }
  hipLaunchKernelGGL(TwoOptMCMC_86148454023515_kernel, dim3(1), dim3(NTHR), 0, stream,
                     bigram, startw, endw, out, gprop);
}

// Round 10
// 5516.425 us; speedup vs baseline: 2.8659x; 1.3377x over previous
//
#include <hip/hip_runtime.h>
#include <stdint.h>
#include <math.h>

#define NW      4096
#define TSTEPS  5722     // BURNIN + (512-1)*11 + 1
#define BURN    100
#define SSTRIDE 11
#define NTHR    256
#define NBOUND  522      // 10 burn-in windows(10) + window(1 @t=100) + 511 windows(11)

struct K2 { uint32_t a, b; };

// Threefry-2x32, 20 rounds — matches jax._src.prng.threefry2x32 exactly.
__device__ __forceinline__ K2 tf(uint32_t k0, uint32_t k1, uint32_t c0, uint32_t c1) {
  uint32_t ks2 = k0 ^ k1 ^ 0x1BD11BDAu;
  uint32_t x0 = c0 + k0, x1 = c1 + k1;
#define RR(r) { x0 += x1; x1 = (x1 << (r)) | (x1 >> (32 - (r))); x1 ^= x0; }
  RR(13) RR(15) RR(26) RR(6)
  x0 += k1;  x1 += ks2 + 1u;
  RR(17) RR(29) RR(16) RR(24)
  x0 += ks2; x1 += k0 + 2u;
  RR(13) RR(15) RR(26) RR(6)
  x0 += k0;  x1 += k1 + 3u;
  RR(17) RR(29) RR(16) RR(24)
  x0 += k1;  x1 += ks2 + 4u;
  RR(13) RR(15) RR(26) RR(6)
  x0 += ks2; x1 += k0 + 5u;
#undef RR
  K2 r; r.a = x0; r.b = x1; return r;
}

__device__ __forceinline__ uint32_t xbits(K2 k) {
  K2 r = tf(k.a, k.b, 0u, 0u);
  return r.a ^ r.b;
}

__device__ __forceinline__ uint32_t ri_off(K2 key, uint32_t span) {
  K2 k1 = tf(key.a, key.b, 0u, 0u);
  K2 k2 = tf(key.a, key.b, 0u, 1u);
  uint32_t hb = xbits(k1);
  uint32_t lb = xbits(k2);
  uint32_t m = 65536u % span;
  m = (m * m) % span;
  return ((hb % span) * m + (lb % span)) % span;
}

__device__ __noinline__ void make_prop(uint32_t kca, uint32_t kcb, int t,
                                       uint32_t& lohi, uint32_t& shv, float& lg) {
  K2 kt = tf(kca, kcb, 0u, (uint32_t)t);
  K2 kl = tf(kt.a, kt.b, 0u, 0u);
  K2 ka = tf(kt.a, kt.b, 0u, 1u);
  K2 kr = tf(kt.a, kt.b, 0u, 2u);
  K2 ku = tf(kt.a, kt.b, 0u, 3u);
  uint32_t l = 1u + ri_off(kl, 4095u);
  uint32_t a = ri_off(ka, 4097u - l);
  uint32_t b = a + l;
  uint32_t r = ri_off(kr, 4096u - l);
  uint32_t c = (b + r + 1u) % 4097u;
  uint32_t lo, hi, sh;
  if (a < c) { lo = a; hi = c; sh = b - a; }
  else       { lo = c; hi = b; sh = a - c; }
  uint32_t ub = xbits(ku);
  float uf = __uint_as_float((ub >> 9) | 0x3F800000u) - 1.0f;
  lohi = lo | (hi << 16);
  shv  = sh;
  lg   = (float)log((double)uf);
}

// smap: post-rotation source map (span = hi-lo).
__device__ __forceinline__ uint32_t smap2(uint32_t i, uint32_t lo, uint32_t span, uint32_t sh) {
  uint32_t t = i - lo;              // wraps huge if i < lo
  uint32_t u = t + sh;
  u = (u >= span) ? u - span : u;   // valid only when t < span
  return (t < span) ? lo + u : i;
}

// grid-parallel proposal precompute -> d_ws (16B records)
__global__ void prop_kernel(uint4* __restrict__ gprop) {
  int t = blockIdx.x * 256 + threadIdx.x;
  if (t >= TSTEPS) return;
  K2 kchain = tf(0u, 42u, 0u, 1u);
  uint32_t lohi, shv; float lg;
  make_prop(kchain.a, kchain.b, t, lohi, shv, lg);
  gprop[t] = make_uint4(lohi, shv, __float_as_uint(lg), 0u);
}

// raw barrier: NO vmcnt drain (keeps speculative global loads in flight)
#define SYNC() do { asm volatile("s_waitcnt lgkmcnt(0)" ::: "memory"); \
                    __builtin_amdgcn_s_barrier(); } while (0)

// f64 cross-lane via DPP on the two 32-bit halves (VALU pipe, no LDS).
template<int CTRL>
__device__ __forceinline__ double dpp_f64(double v) {
  long long s = __double_as_longlong(v);
  int lo = (int)(s & 0xFFFFFFFFll);
  int hi = (int)(s >> 32);
  lo = __builtin_amdgcn_update_dpp(0, lo, CTRL, 0xF, 0xF, true);
  hi = __builtin_amdgcn_update_dpp(0, hi, CTRL, 0xF, 0xF, true);
  return __longlong_as_double((long long)(unsigned)lo | ((long long)hi << 32));
}

// compose through accepted-move stack (newest first), cost ∝ jc (uniform switch).
__device__ __forceinline__ uint32_t compose_sw(uint32_t pos, int jc,
                                               const uint32_t (&mlh)[12],
                                               const uint32_t (&msh)[12]) {
  switch (jc) {
    case 11: pos = smap2(pos, mlh[10] & 0xFFFFu, mlh[10] >> 16, msh[10]); [[fallthrough]];
    case 10: pos = smap2(pos, mlh[9]  & 0xFFFFu, mlh[9]  >> 16, msh[9]);  [[fallthrough]];
    case 9:  pos = smap2(pos, mlh[8]  & 0xFFFFu, mlh[8]  >> 16, msh[8]);  [[fallthrough]];
    case 8:  pos = smap2(pos, mlh[7]  & 0xFFFFu, mlh[7]  >> 16, msh[7]);  [[fallthrough]];
    case 7:  pos = smap2(pos, mlh[6]  & 0xFFFFu, mlh[6]  >> 16, msh[6]);  [[fallthrough]];
    case 6:  pos = smap2(pos, mlh[5]  & 0xFFFFu, mlh[5]  >> 16, msh[5]);  [[fallthrough]];
    case 5:  pos = smap2(pos, mlh[4]  & 0xFFFFu, mlh[4]  >> 16, msh[4]);  [[fallthrough]];
    case 4:  pos = smap2(pos, mlh[3]  & 0xFFFFu, mlh[3]  >> 16, msh[3]);  [[fallthrough]];
    case 3:  pos = smap2(pos, mlh[2]  & 0xFFFFu, mlh[2]  >> 16, msh[2]);  [[fallthrough]];
    case 2:  pos = smap2(pos, mlh[1]  & 0xFFFFu, mlh[1]  >> 16, msh[1]);  [[fallthrough]];
    case 1:  pos = smap2(pos, mlh[0]  & 0xFFFFu, mlh[0]  >> 16, msh[0]);  break;
    default: break;
  }
  return pos;
}

// materialize new base = old base ∘ stack (params from LDS, uniform); emit row.
__device__ __forceinline__ void mat_emit(int tid, int jcu, uint32_t cur,
                                         const uint32_t* __restrict__ s_mvlh,
                                         const uint32_t* __restrict__ s_mvsh,
                                         uint32_t (*s_base)[NW],
                                         bool emit, int row, int* __restrict__ out) {
  uint32_t posa[16];
  #pragma unroll
  for (int k = 0; k < 16; ++k) posa[k] = (uint32_t)tid + (uint32_t)k * 256u;
  for (int j = jcu - 1; j >= 0; --j) {        // scalar loop, newest first
    uint32_t lh = s_mvlh[j], sh = s_mvsh[j];  // uniform LDS broadcast
    uint32_t lo = lh & 0xFFFFu, sp = lh >> 16;
    #pragma unroll
    for (int k = 0; k < 16; ++k) posa[k] = smap2(posa[k], lo, sp, sh);
  }
  uint32_t vals[16];
  #pragma unroll
  for (int k = 0; k < 16; ++k) vals[k] = s_base[cur][posa[k]];
  #pragma unroll
  for (int k = 0; k < 16; ++k) {
    uint32_t i = (uint32_t)tid + (uint32_t)k * 256u;
    s_base[cur ^ 1u][i] = vals[k];
    if (emit) out[(size_t)row * NW + i] = (int)vals[k];
  }
}

// one MCMC step on wave 0, all lanes cooperating. Consumes ld (loads issued
// at T-2), refills it with speculative loads for T+2. Barrier-free.
__device__ __forceinline__ void stepf(
    int T, uint32_t lane, float sgn, float& ld, bool& accp, int& jc,
    uint32_t (&mlh)[12], uint32_t (&msh)[12],
    uint32_t& s0lh, uint32_t& s0sh, float& s0lg,
    uint32_t& s1lh, uint32_t& s1sh, float& s1lg,
    uint32_t& s2lh, uint32_t& s2sh, float& s2lg,
    uint32_t& s3lh, uint32_t& s3sh, float& s3lg,
    const uint32_t* __restrict__ sbase,
    uint32_t* __restrict__ s_mvlh, uint32_t* __restrict__ s_mvsh,
    const float* __restrict__ bigram, const float* __restrict__ startw,
    const float* __restrict__ endw, const uint4* __restrict__ gprop,
    uint32_t kca, uint32_t kcb) {

  uint32_t p    = lane & 7u;
  uint32_t vset = (lane >> 3) & 3u;   // 0=RR 1=RA(S_{T+1}) 2=AR(S_T) 3=AA

  // positions g from proposal T+2 (slot 2)
  uint32_t lo2 = s2lh & 0xFFFFu, hi2 = s2lh >> 16, sh2 = s2sh;
  uint32_t g0 = lo2, g1 = lo2 + sh2, g2v = g1 - 1u, g3 = hi2 - 1u;
  uint32_t g4 = (lo2 > 0u) ? lo2 - 1u : 0u;
  uint32_t g5 = (hi2 < (uint32_t)NW) ? hi2 : 0u;
  uint32_t pos = (p == 0u) ? g0 : (p == 1u) ? g1 : (p == 2u) ? g2v
               : (p == 3u) ? g3 : (p == 4u) ? g4 : g5;

  uint32_t lo1 = s1lh & 0xFFFFu, sp1 = (s1lh >> 16) - lo1, sh1 = s1sh;
  uint32_t lo0 = s0lh & 0xFFFFu, sp0 = (s0lh >> 16) - lo0, sh0 = s0sh;
  if (vset & 1u) pos = smap2(pos, lo1, sp1, sh1);
  if (vset & 2u) pos = smap2(pos, lo0, sp0, sh0);
  pos = compose_sw(pos, jc, mlh, msh);
  uint32_t val = sbase[pos];                    // one ds_read, 32 lanes

  // prefetch proposal T+4 (slot3 holds T+3 at entry)
  int tq = T + 4; if (tq > TSTEPS - 1) tq = TSTEPS - 1;
  uint32_t nlh, nsh; float nlg;
  if (gprop) { uint4 gp = gprop[tq]; nlh = gp.x; nsh = gp.y; nlg = __uint_as_float(gp.z); }
  else       { make_prop(kca, kcb, tq, nlh, nsh, nlg); }

  // ---- decision for T: DPP reduction of both variants (VALU pipe only) ----
  // ld: lanes 0-5 = reject-variant values, lanes 8-13 = accept-variant values.
  // row_shr accumulates at HIGH lanes: lane7 = sum(lanes0-7) = d_R,
  // lane15 = sum(lanes8-15) = d_A (no cross-contamination into lane 15).
  double du = (double)(ld * sgn);      // sgn = 0 for p>=6, ±1 alternating else
  du += dpp_f64<0x111>(du);            // row_shr:1
  du += dpp_f64<0x112>(du);            // row_shr:2
  du += dpp_f64<0x114>(du);            // row_shr:4
  double dmin = du < 0.0 ? du : 0.0;
  int accl = (dmin > (double)s0lg) ? 1 : 0;
  int accR = __builtin_amdgcn_readlane(accl, 7);    // reject-variant decision
  int accA = __builtin_amdgcn_readlane(accl, 15);   // accept-variant decision
  int acc = accp ? accA : accR;                     // scalar, uniform

  // ---- select Q values, issue 12 loads for T+2 (lanes 0-5, 8-13) ----
  uint32_t qv = (uint32_t)__shfl((int)val, (int)((uint32_t)acc * 16u + lane), 64);
  uint32_t base8 = lane & ~7u;
  uint32_t rsrc = (p == 0u) ? 3u : (p == 1u) ? 2u : (p <= 3u) ? 4u : (p == 4u) ? 2u : 3u;
  uint32_t csrc = (p == 0u) ? 0u : (p <= 2u) ? 1u : (p == 3u) ? 0u : 5u;
  uint32_t row = (uint32_t)__shfl((int)qv, (int)(base8 + rsrc), 64);
  uint32_t col = (uint32_t)__shfl((int)qv, (int)(base8 + csrc), 64);
  bool isbi = (p < 2u) || ((p < 4u) ? (lo2 > 0u) : (hi2 < (uint32_t)NW));
  const float* addr = isbi ? (bigram + (size_t)row * NW + col)
                           : ((p < 4u) ? (startw + col) : (endw + row));
  bool isload = (vset < 2u) && (p < 6u);
  if (isload) ld = *addr;

  // ---- bookkeeping (acc scalar => uniform branches; static stack indices) ----
  if (acc) {
    uint32_t nv = lo0 | (sp0 << 16);
    switch (jc) {
      case 0:  mlh[0]  = nv; msh[0]  = sh0; break;
      case 1:  mlh[1]  = nv; msh[1]  = sh0; break;
      case 2:  mlh[2]  = nv; msh[2]  = sh0; break;
      case 3:  mlh[3]  = nv; msh[3]  = sh0; break;
      case 4:  mlh[4]  = nv; msh[4]  = sh0; break;
      case 5:  mlh[5]  = nv; msh[5]  = sh0; break;
      case 6:  mlh[6]  = nv; msh[6]  = sh0; break;
      case 7:  mlh[7]  = nv; msh[7]  = sh0; break;
      case 8:  mlh[8]  = nv; msh[8]  = sh0; break;
      case 9:  mlh[9]  = nv; msh[9]  = sh0; break;
      case 10: mlh[10] = nv; msh[10] = sh0; break;
      default: break;
    }
    if (lane == 0u) { s_mvlh[jc] = nv; s_mvsh[jc] = sh0; }
    jc++;
  }
  accp = (acc != 0);

  // shift proposal slots
  s0lh = s1lh; s0sh = s1sh; s0lg = s1lg;
  s1lh = s2lh; s1sh = s2sh; s1lg = s2lg;
  s2lh = s3lh; s2sh = s3sh; s2lg = s3lg;
  s3lh = nlh;  s3sh = nsh;  s3lg = nlg;
}

__global__ __launch_bounds__(NTHR)
void TwoOptMCMC_86148454023515_kernel(const float* __restrict__ bigram,
                                      const float* __restrict__ startw,
                                      const float* __restrict__ endw,
                                      int* __restrict__ out,
                                      const uint4* __restrict__ gprop) {
  __shared__ __align__(16) uint32_t s_base[2][NW];   // 32 KB ping-pong; aliased for init sort
  __shared__ uint32_t s_mvlh[12];
  __shared__ uint32_t s_mvsh[12];
  __shared__ uint32_t s_jc[1];

  unsigned long long* s_comp = (unsigned long long*)s_base;
  const int tid = threadIdx.x;
  K2 kinit  = tf(0u, 42u, 0u, 0u);
  K2 kchain = tf(0u, 42u, 0u, 1u);

  // ---- initial permutation: 2-round stable-sort shuffle ----
  {
    K2 kc = kinit;
    for (int rnd = 0; rnd < 2; ++rnd) {
      K2 knext = tf(kc.a, kc.b, 0u, 0u);
      K2 ksub  = tf(kc.a, kc.b, 0u, 1u);
      for (int i = tid; i < NW; i += NTHR) {
        K2 r = tf(ksub.a, ksub.b, 0u, (uint32_t)i);
        uint32_t sk = r.a ^ r.b;
        unsigned long long pv = (rnd == 0) ? (unsigned long long)(uint32_t)i
                                           : (s_comp[i] & 0xFFFull);
        s_comp[i] = ((unsigned long long)sk << 24) |
                    ((unsigned long long)(uint32_t)i << 12) | pv;
      }
      __syncthreads();
      for (int k = 2; k <= NW; k <<= 1) {
        for (int j = k >> 1; j > 0; j >>= 1) {
          for (int i = tid; i < NW; i += NTHR) {
            int ixj = i ^ j;
            if (ixj > i) {
              unsigned long long va = s_comp[i], vb = s_comp[ixj];
              bool up = ((i & k) == 0);
              if ((va > vb) == up) { s_comp[i] = vb; s_comp[ixj] = va; }
            }
          }
          __syncthreads();
        }
      }
      kc = knext;
    }
    uint32_t pv[16];
    #pragma unroll
    for (int k = 0; k < 16; ++k) pv[k] = (uint32_t)(s_comp[tid + k * 256] & 0xFFFull);
    __syncthreads();
    #pragma unroll
    for (int k = 0; k < 16; ++k) s_base[0][tid + k * 256] = pv[k];
    __syncthreads();
  }

  const int wave = tid >> 6;
  const uint32_t lane = (uint32_t)(tid & 63);

  if (wave == 0) {
    // ---- wave 0: barrier-free MCMC windows ----
    uint32_t mlh[12], msh[12];
    #pragma unroll
    for (int k = 0; k < 12; ++k) { mlh[k] = 0u; msh[k] = 0u; }
    int jc = 0; bool accp = false; uint32_t cur = 0u;
    float ldA = 0.f, ldB = 0.f;

    uint32_t s0lh, s0sh, s1lh, s1sh, s2lh, s2sh, s3lh, s3sh;
    float s0lg, s1lg, s2lg, s3lg;
    {
      uint32_t lh[4], sh[4]; float lg[4];
      #pragma unroll
      for (int j = 0; j < 4; ++j) {
        int tq = j; if (tq > TSTEPS - 1) tq = TSTEPS - 1;
        if (gprop) { uint4 gp = gprop[tq]; lh[j] = gp.x; sh[j] = gp.y; lg[j] = __uint_as_float(gp.z); }
        else       { make_prop(kchain.a, kchain.b, tq, lh[j], sh[j], lg[j]); }
      }
      s0lh = lh[0]; s0sh = sh[0]; s0lg = lg[0];
      s1lh = lh[1]; s1sh = sh[1]; s1lg = lg[1];
      s2lh = lh[2]; s2sh = sh[2]; s2lg = lg[2];
      s3lh = lh[3]; s3sh = sh[3]; s3lg = lg[3];
    }

    uint32_t p = lane & 7u;
    uint32_t vset = (lane >> 3) & 3u;
    float sgn = (p >= 6u) ? 0.f : ((p & 1u) ? -1.f : 1.f);
    uint32_t rsrc = (p == 0u) ? 3u : (p == 1u) ? 2u : (p <= 3u) ? 4u : (p == 4u) ? 2u : 3u;
    uint32_t csrc = (p == 0u) ? 0u : (p <= 2u) ? 1u : (p == 3u) ? 0u : 5u;
    bool isload = (vset < 2u) && (p < 6u);
    uint32_t base8 = lane & ~7u;

    // prologue A: loads for t=0, direct from P_0 (both sets identical)
    {
      uint32_t lo2 = s0lh & 0xFFFFu, hi2 = s0lh >> 16, sh2 = s0sh;
      uint32_t g0 = lo2, g1 = lo2 + sh2, g2v = g1 - 1u, g3 = hi2 - 1u;
      uint32_t g4 = (lo2 > 0u) ? lo2 - 1u : 0u;
      uint32_t g5 = (hi2 < (uint32_t)NW) ? hi2 : 0u;
      uint32_t pos = (p == 0u) ? g0 : (p == 1u) ? g1 : (p == 2u) ? g2v
                   : (p == 3u) ? g3 : (p == 4u) ? g4 : g5;
      uint32_t val = s_base[0][pos];
      uint32_t row = (uint32_t)__shfl((int)val, (int)(base8 + rsrc), 64);
      uint32_t col = (uint32_t)__shfl((int)val, (int)(base8 + csrc), 64);
      bool isbi = (p < 2u) || ((p < 4u) ? (lo2 > 0u) : (hi2 < (uint32_t)NW));
      const float* addr = isbi ? (bigram + (size_t)row * NW + col)
                               : ((p < 4u) ? (startw + col) : (endw + row));
      if (isload) ldA = *addr;
    }
    // prologue B: loads for t=1; set1 composes S_0
    {
      uint32_t lo2 = s1lh & 0xFFFFu, hi2 = s1lh >> 16, sh2 = s1sh;
      uint32_t g0 = lo2, g1 = lo2 + sh2, g2v = g1 - 1u, g3 = hi2 - 1u;
      uint32_t g4 = (lo2 > 0u) ? lo2 - 1u : 0u;
      uint32_t g5 = (hi2 < (uint32_t)NW) ? hi2 : 0u;
      uint32_t pos = (p == 0u) ? g0 : (p == 1u) ? g1 : (p == 2u) ? g2v
                   : (p == 3u) ? g3 : (p == 4u) ? g4 : g5;
      uint32_t lo0 = s0lh & 0xFFFFu, sp0 = (s0lh >> 16) - lo0, sh0 = s0sh;
      if (vset & 1u) pos = smap2(pos, lo0, sp0, sh0);
      uint32_t val = s_base[0][pos];
      uint32_t row = (uint32_t)__shfl((int)val, (int)(base8 + rsrc), 64);
      uint32_t col = (uint32_t)__shfl((int)val, (int)(base8 + csrc), 64);
      bool isbi = (p < 2u) || ((p < 4u) ? (lo2 > 0u) : (hi2 < (uint32_t)NW));
      const float* addr = isbi ? (bigram + (size_t)row * NW + col)
                               : ((p < 4u) ? (startw + col) : (endw + row));
      if (isload) ldB = *addr;
    }

    int t = 0;
    for (int b = 0; b < NBOUND; ++b) {
      int wlen = (b < 10) ? 10 : ((b == 10) ? 1 : 11);
      const uint32_t* sb = s_base[cur];
      #pragma unroll
      for (int k = 0; k < 11; ++k) {
        if (k < wlen) {
          if ((k & 1) == 0)
            stepf(t + k, lane, sgn, ldA, accp, jc, mlh, msh,
                  s0lh, s0sh, s0lg, s1lh, s1sh, s1lg, s2lh, s2sh, s2lg,
                  s3lh, s3sh, s3lg, sb, s_mvlh, s_mvsh,
                  bigram, startw, endw, gprop, kchain.a, kchain.b);
          else
            stepf(t + k, lane, sgn, ldB, accp, jc, mlh, msh,
                  s0lh, s0sh, s0lg, s1lh, s1sh, s1lg, s2lh, s2sh, s2lg,
                  s3lh, s3sh, s3lg, sb, s_mvlh, s_mvsh,
                  bigram, startw, endw, gprop, kchain.a, kchain.b);
        }
      }
      if (lane == 0u) s_jc[0] = (uint32_t)jc;
      SYNC();                                       // publish move list
      mat_emit(tid, jc, cur, s_mvlh, s_mvsh, s_base, b >= 10, b - 10, out);
      SYNC();                                       // new base complete
      if (wlen & 1) { float tmp = ldA; ldA = ldB; ldB = tmp; }  // loads long done
      jc = 0; cur ^= 1u; t += wlen;
    }
  } else {
    // ---- waves 1-3: parked; materialize + emit at each boundary ----
    for (int b = 0; b < NBOUND; ++b) {
      SYNC();
      int jcu = __builtin_amdgcn_readfirstlane((int)s_jc[0]);
      mat_emit(tid, jcu, (uint32_t)(b & 1), s_mvlh, s_mvsh, s_base, b >= 10, b - 10, out);
      SYNC();
    }
  }
}

extern "C" void kernel_launch(void* const* d_in, const int* in_sizes, int n_in,
                              void* d_out, int out_size, void* d_ws, size_t ws_size,
                              hipStream_t stream) {
  (void)in_sizes; (void)n_in; (void)out_size;
  const float* bigram = (const float*)d_in[1];
  const float* startw = (const float*)d_in[2];
  const float* endw   = (const float*)d_in[3];
  int* out = (int*)d_out;
  uint4* gprop = nullptr;
  if (ws_size >= (size_t)TSTEPS * 16) {
    gprop = (uint4*)d_ws;
    hipLaunchKernelGGL(prop_kernel, dim3((TSTEPS + 255) / 256), dim3(256), 0, stream, gprop);
  }
  hipLaunchKernelGGL(TwoOptMCMC_86148454023515_kernel, dim3(1), dim3(NTHR), 0, stream,
                     bigram, startw, endw, out, gprop);
}

// Round 11
// 4613.649 us; speedup vs baseline: 3.4266x; 1.1957x over previous
//
#include <hip/hip_runtime.h>
#include <stdint.h>
#include <math.h>

#define NW      4096
#define TSTEPS  5722     // BURNIN + (512-1)*11 + 1
#define BURN    100
#define SSTRIDE 11
#define NTHR    256
#define NBOUND  522      // 10 windows(10) + 1 window(1 @t=100) + 511 windows(11)

struct K2 { uint32_t a, b; };

// Threefry-2x32, 20 rounds — matches jax._src.prng.threefry2x32 exactly.
__device__ __forceinline__ K2 tf(uint32_t k0, uint32_t k1, uint32_t c0, uint32_t c1) {
  uint32_t ks2 = k0 ^ k1 ^ 0x1BD11BDAu;
  uint32_t x0 = c0 + k0, x1 = c1 + k1;
#define RR(r) { x0 += x1; x1 = (x1 << (r)) | (x1 >> (32 - (r))); x1 ^= x0; }
  RR(13) RR(15) RR(26) RR(6)
  x0 += k1;  x1 += ks2 + 1u;
  RR(17) RR(29) RR(16) RR(24)
  x0 += ks2; x1 += k0 + 2u;
  RR(13) RR(15) RR(26) RR(6)
  x0 += k0;  x1 += k1 + 3u;
  RR(17) RR(29) RR(16) RR(24)
  x0 += k1;  x1 += ks2 + 4u;
  RR(13) RR(15) RR(26) RR(6)
  x0 += ks2; x1 += k0 + 5u;
#undef RR
  K2 r; r.a = x0; r.b = x1; return r;
}

__device__ __forceinline__ uint32_t xbits(K2 k) {
  K2 r = tf(k.a, k.b, 0u, 0u);
  return r.a ^ r.b;
}

__device__ __forceinline__ uint32_t ri_off(K2 key, uint32_t span) {
  K2 k1 = tf(key.a, key.b, 0u, 0u);
  K2 k2 = tf(key.a, key.b, 0u, 1u);
  uint32_t hb = xbits(k1);
  uint32_t lb = xbits(k2);
  uint32_t m = 65536u % span;
  m = (m * m) % span;
  return ((hb % span) * m + (lb % span)) % span;
}

__device__ __noinline__ void make_prop(uint32_t kca, uint32_t kcb, int t,
                                       uint32_t& lohi, uint32_t& shv, float& lg) {
  K2 kt = tf(kca, kcb, 0u, (uint32_t)t);
  K2 kl = tf(kt.a, kt.b, 0u, 0u);
  K2 ka = tf(kt.a, kt.b, 0u, 1u);
  K2 kr = tf(kt.a, kt.b, 0u, 2u);
  K2 ku = tf(kt.a, kt.b, 0u, 3u);
  uint32_t l = 1u + ri_off(kl, 4095u);
  uint32_t a = ri_off(ka, 4097u - l);
  uint32_t b = a + l;
  uint32_t r = ri_off(kr, 4096u - l);
  uint32_t c = (b + r + 1u) % 4097u;
  uint32_t lo, hi, sh;
  if (a < c) { lo = a; hi = c; sh = b - a; }
  else       { lo = c; hi = b; sh = a - c; }
  uint32_t ub = xbits(ku);
  float uf = __uint_as_float((ub >> 9) | 0x3F800000u) - 1.0f;
  lohi = lo | (hi << 16);
  shv  = sh;
  lg   = (float)log((double)uf);
}

// smap: post-rotation source map (span = hi-lo).
__device__ __forceinline__ uint32_t smap2(uint32_t i, uint32_t lo, uint32_t span, uint32_t sh) {
  uint32_t t = i - lo;              // wraps huge if i < lo
  uint32_t u = t + sh;
  u = (u >= span) ? u - span : u;   // valid only when t < span
  return (t < span) ? lo + u : i;
}

// grid-parallel proposal precompute -> d_ws (16B records)
__global__ void prop_kernel(uint4* __restrict__ gprop) {
  int t = blockIdx.x * 256 + threadIdx.x;
  if (t >= TSTEPS) return;
  K2 kchain = tf(0u, 42u, 0u, 1u);
  uint32_t lohi, shv; float lg;
  make_prop(kchain.a, kchain.b, t, lohi, shv, lg);
  gprop[t] = make_uint4(lohi, shv, __float_as_uint(lg), 0u);
}

// raw barrier: NO vmcnt drain (keeps speculative global loads in flight)
#define SYNC() do { asm volatile("s_waitcnt lgkmcnt(0)" ::: "memory"); \
                    __builtin_amdgcn_s_barrier(); } while (0)

// f64 cross-lane via DPP on the two 32-bit halves (VALU pipe, no LDS).
template<int CTRL>
__device__ __forceinline__ double dpp_f64(double v) {
  long long s = __double_as_longlong(v);
  int lo = (int)(s & 0xFFFFFFFFll);
  int hi = (int)(s >> 32);
  lo = __builtin_amdgcn_update_dpp(0, lo, CTRL, 0xF, 0xF, true);
  hi = __builtin_amdgcn_update_dpp(0, hi, CTRL, 0xF, 0xF, true);
  return __longlong_as_double((long long)(unsigned)lo | ((long long)hi << 32));
}

// compose through accepted-move stack (newest first), cost ∝ jc (uniform switch).
__device__ __forceinline__ uint32_t compose_sw(uint32_t pos, int jc,
                                               const uint32_t (&mlh)[12],
                                               const uint32_t (&msh)[12]) {
  switch (jc) {
    case 11: pos = smap2(pos, mlh[10] & 0xFFFFu, mlh[10] >> 16, msh[10]); [[fallthrough]];
    case 10: pos = smap2(pos, mlh[9]  & 0xFFFFu, mlh[9]  >> 16, msh[9]);  [[fallthrough]];
    case 9:  pos = smap2(pos, mlh[8]  & 0xFFFFu, mlh[8]  >> 16, msh[8]);  [[fallthrough]];
    case 8:  pos = smap2(pos, mlh[7]  & 0xFFFFu, mlh[7]  >> 16, msh[7]);  [[fallthrough]];
    case 7:  pos = smap2(pos, mlh[6]  & 0xFFFFu, mlh[6]  >> 16, msh[6]);  [[fallthrough]];
    case 6:  pos = smap2(pos, mlh[5]  & 0xFFFFu, mlh[5]  >> 16, msh[5]);  [[fallthrough]];
    case 5:  pos = smap2(pos, mlh[4]  & 0xFFFFu, mlh[4]  >> 16, msh[4]);  [[fallthrough]];
    case 4:  pos = smap2(pos, mlh[3]  & 0xFFFFu, mlh[3]  >> 16, msh[3]);  [[fallthrough]];
    case 3:  pos = smap2(pos, mlh[2]  & 0xFFFFu, mlh[2]  >> 16, msh[2]);  [[fallthrough]];
    case 2:  pos = smap2(pos, mlh[1]  & 0xFFFFu, mlh[1]  >> 16, msh[1]);  [[fallthrough]];
    case 1:  pos = smap2(pos, mlh[0]  & 0xFFFFu, mlh[0]  >> 16, msh[0]);  break;
    default: break;
  }
  return pos;
}

// materialize new base = old base ∘ stack (params from LDS, uniform); emit row.
__device__ __forceinline__ void mat_emit(int tid, int jcu, uint32_t cur,
                                         const uint32_t* __restrict__ s_mvlh,
                                         const uint32_t* __restrict__ s_mvsh,
                                         uint32_t (*s_base)[NW],
                                         bool emit, int row, int* __restrict__ out) {
  uint32_t posa[16];
  #pragma unroll
  for (int k = 0; k < 16; ++k) posa[k] = (uint32_t)tid + (uint32_t)k * 256u;
  for (int j = jcu - 1; j >= 0; --j) {        // scalar loop, newest first
    uint32_t lh = s_mvlh[j], sh = s_mvsh[j];  // uniform LDS broadcast
    uint32_t lo = lh & 0xFFFFu, sp = lh >> 16;
    #pragma unroll
    for (int k = 0; k < 16; ++k) posa[k] = smap2(posa[k], lo, sp, sh);
  }
  uint32_t vals[16];
  #pragma unroll
  for (int k = 0; k < 16; ++k) vals[k] = s_base[cur][posa[k]];
  #pragma unroll
  for (int k = 0; k < 16; ++k) {
    uint32_t i = (uint32_t)tid + (uint32_t)k * 256u;
    s_base[cur ^ 1u][i] = vals[k];
    if (emit) out[(size_t)row * NW + i] = (int)vals[k];
  }
}

// one MCMC step on wave 0. K = step index within window (compile-time).
// Proposal slots come from the lane-batched registers via constant readlane.
// Consumes ld (issued 2 steps ago), refills it for step K+2. Barrier-free.
template<int K>
__device__ __forceinline__ void stepf(
    uint32_t lane, float sgn, float& ld, bool& accp, int& jc,
    uint32_t (&mlh)[12], uint32_t (&msh)[12],
    uint32_t cAlh, uint32_t cAsh, float cAlg,
    const uint32_t* __restrict__ sbase,
    uint32_t* __restrict__ s_mvlh, uint32_t* __restrict__ s_mvsh,
    const float* __restrict__ bigram, const float* __restrict__ startw,
    const float* __restrict__ endw,
    uint32_t rsrc, uint32_t csrc, bool isload, uint32_t base8) {

  uint32_t p = lane & 7u;
  uint32_t vset = (lane >> 3) & 3u;   // 0=RR 1=RA(S_{T+1}) 2=AR(S_T) 3=AA

  // proposal slots (constant-index readlane -> SGPRs; position math on SALU)
  uint32_t s0lh = (uint32_t)__builtin_amdgcn_readlane((int)cAlh, K);
  uint32_t s0sh = (uint32_t)__builtin_amdgcn_readlane((int)cAsh, K);
  float    s0lg = __uint_as_float((uint32_t)__builtin_amdgcn_readlane(
                      (int)__float_as_uint(cAlg), K));
  uint32_t s1lh = (uint32_t)__builtin_amdgcn_readlane((int)cAlh, K + 1);
  uint32_t s1sh = (uint32_t)__builtin_amdgcn_readlane((int)cAsh, K + 1);
  uint32_t s2lh = (uint32_t)__builtin_amdgcn_readlane((int)cAlh, K + 2);
  uint32_t s2sh = (uint32_t)__builtin_amdgcn_readlane((int)cAsh, K + 2);

  // positions g from proposal T+2
  uint32_t lo2 = s2lh & 0xFFFFu, hi2 = s2lh >> 16, sh2 = s2sh;
  uint32_t g0 = lo2, g1 = lo2 + sh2, g2v = g1 - 1u, g3 = hi2 - 1u;
  uint32_t g4 = (lo2 > 0u) ? lo2 - 1u : 0u;
  uint32_t g5 = (hi2 < (uint32_t)NW) ? hi2 : 0u;
  uint32_t pos = (p == 0u) ? g0 : (p == 1u) ? g1 : (p == 2u) ? g2v
               : (p == 3u) ? g3 : (p == 4u) ? g4 : g5;

  uint32_t lo1 = s1lh & 0xFFFFu, sp1 = (s1lh >> 16) - lo1, sh1 = s1sh;
  uint32_t lo0 = s0lh & 0xFFFFu, sp0 = (s0lh >> 16) - lo0, sh0 = s0sh;
  if (vset & 1u) pos = smap2(pos, lo1, sp1, sh1);
  if (vset & 2u) pos = smap2(pos, lo0, sp0, sh0);
  pos = compose_sw(pos, jc, mlh, msh);
  uint32_t val = sbase[pos];                    // one ds_read, 32 lanes

  // ---- decision for T: DPP reduction (VALU pipe only) ----
  // row_shr accumulates at HIGH lanes: lane7 = d_R, lane15 = d_A.
  double du = (double)(ld * sgn);
  du += dpp_f64<0x111>(du);            // row_shr:1
  du += dpp_f64<0x112>(du);            // row_shr:2
  du += dpp_f64<0x114>(du);            // row_shr:4
  double dmin = du < 0.0 ? du : 0.0;
  int accl = (dmin > (double)s0lg) ? 1 : 0;
  int accR = __builtin_amdgcn_readlane(accl, 7);
  int accA = __builtin_amdgcn_readlane(accl, 15);
  int acc = accp ? accA : accR;                 // scalar, uniform

  // ---- row/col with accept-select folded into the shuffle index ----
  uint32_t selb = (uint32_t)acc * 16u + base8;
  uint32_t row = (uint32_t)__shfl((int)val, (int)(selb + rsrc), 64);
  uint32_t col = (uint32_t)__shfl((int)val, (int)(selb + csrc), 64);
  bool isbi = (p < 2u) || ((p < 4u) ? (lo2 > 0u) : (hi2 < (uint32_t)NW));
  const float* addr = isbi ? (bigram + (size_t)row * NW + col)
                           : ((p < 4u) ? (startw + col) : (endw + row));
  if (isload) ld = *addr;

  // ---- bookkeeping (acc scalar => uniform branches; static stack indices) ----
  if (acc) {
    uint32_t nv = lo0 | (sp0 << 16);
    switch (jc) {
      case 0:  mlh[0]  = nv; msh[0]  = sh0; break;
      case 1:  mlh[1]  = nv; msh[1]  = sh0; break;
      case 2:  mlh[2]  = nv; msh[2]  = sh0; break;
      case 3:  mlh[3]  = nv; msh[3]  = sh0; break;
      case 4:  mlh[4]  = nv; msh[4]  = sh0; break;
      case 5:  mlh[5]  = nv; msh[5]  = sh0; break;
      case 6:  mlh[6]  = nv; msh[6]  = sh0; break;
      case 7:  mlh[7]  = nv; msh[7]  = sh0; break;
      case 8:  mlh[8]  = nv; msh[8]  = sh0; break;
      case 9:  mlh[9]  = nv; msh[9]  = sh0; break;
      case 10: mlh[10] = nv; msh[10] = sh0; break;
      default: break;
    }
    if (lane == 0u) { s_mvlh[jc] = nv; s_mvsh[jc] = sh0; }
    jc++;
  }
  accp = (acc != 0);
}

__global__ __launch_bounds__(NTHR)
void TwoOptMCMC_86148454023515_kernel(const float* __restrict__ bigram,
                                      const float* __restrict__ startw,
                                      const float* __restrict__ endw,
                                      int* __restrict__ out,
                                      const uint4* __restrict__ gprop) {
  __shared__ __align__(16) uint32_t s_base[2][NW];   // 32 KB ping-pong; aliased for init sort
  __shared__ uint32_t s_mvlh[12];
  __shared__ uint32_t s_mvsh[12];
  __shared__ uint32_t s_jc[1];

  unsigned long long* s_comp = (unsigned long long*)s_base;
  const int tid = threadIdx.x;
  K2 kinit  = tf(0u, 42u, 0u, 0u);
  K2 kchain = tf(0u, 42u, 0u, 1u);

  // ---- initial permutation: 2-round stable-sort shuffle ----
  {
    K2 kc = kinit;
    for (int rnd = 0; rnd < 2; ++rnd) {
      K2 knext = tf(kc.a, kc.b, 0u, 0u);
      K2 ksub  = tf(kc.a, kc.b, 0u, 1u);
      for (int i = tid; i < NW; i += NTHR) {
        K2 r = tf(ksub.a, ksub.b, 0u, (uint32_t)i);
        uint32_t sk = r.a ^ r.b;
        unsigned long long pv = (rnd == 0) ? (unsigned long long)(uint32_t)i
                                           : (s_comp[i] & 0xFFFull);
        s_comp[i] = ((unsigned long long)sk << 24) |
                    ((unsigned long long)(uint32_t)i << 12) | pv;
      }
      __syncthreads();
      for (int k = 2; k <= NW; k <<= 1) {
        for (int j = k >> 1; j > 0; j >>= 1) {
          for (int i = tid; i < NW; i += NTHR) {
            int ixj = i ^ j;
            if (ixj > i) {
              unsigned long long va = s_comp[i], vb = s_comp[ixj];
              bool up = ((i & k) == 0);
              if ((va > vb) == up) { s_comp[i] = vb; s_comp[ixj] = va; }
            }
          }
          __syncthreads();
        }
      }
      kc = knext;
    }
    uint32_t pv[16];
    #pragma unroll
    for (int k = 0; k < 16; ++k) pv[k] = (uint32_t)(s_comp[tid + k * 256] & 0xFFFull);
    __syncthreads();
    #pragma unroll
    for (int k = 0; k < 16; ++k) s_base[0][tid + k * 256] = pv[k];
    __syncthreads();
  }

  const int wave = tid >> 6;
  const uint32_t lane = (uint32_t)(tid & 63);

  if (wave == 0) {
    // ---- wave 0: barrier-free MCMC windows, lane-batched proposals ----
    uint32_t mlh[12], msh[12];
    #pragma unroll
    for (int k = 0; k < 12; ++k) { mlh[k] = 0u; msh[k] = 0u; }
    int jc = 0; bool accp = false; uint32_t cur = 0u;
    float ldA = 0.f, ldB = 0.f;

    uint32_t p = lane & 7u;
    uint32_t vset = (lane >> 3) & 3u;
    float sgn = (p >= 6u) ? 0.f : ((p & 1u) ? -1.f : 1.f);
    uint32_t rsrc = (p == 0u) ? 3u : (p == 1u) ? 2u : (p <= 3u) ? 4u : (p == 4u) ? 2u : 3u;
    uint32_t csrc = (p == 0u) ? 0u : (p <= 2u) ? 1u : (p == 3u) ? 0u : 5u;
    bool isload = (vset < 2u) && (p < 6u);
    uint32_t base8 = lane & ~7u;

    // batch for window 0 (lane i = proposal i, i<14)
    uint32_t cAlh, cAsh; float cAlg;
    {
      int idx = (int)(lane < 14u ? lane : 13u);
      if (gprop) { uint4 gp = gprop[idx]; cAlh = gp.x; cAsh = gp.y; cAlg = __uint_as_float(gp.z); }
      else       { make_prop(kchain.a, kchain.b, idx, cAlh, cAsh, cAlg); }
    }

    // prologue A: loads for t=0, direct from P_0
    {
      uint32_t s0lh = (uint32_t)__builtin_amdgcn_readlane((int)cAlh, 0);
      uint32_t s0sh = (uint32_t)__builtin_amdgcn_readlane((int)cAsh, 0);
      uint32_t lo2 = s0lh & 0xFFFFu, hi2 = s0lh >> 16, sh2 = s0sh;
      uint32_t g0 = lo2, g1 = lo2 + sh2, g2v = g1 - 1u, g3 = hi2 - 1u;
      uint32_t g4 = (lo2 > 0u) ? lo2 - 1u : 0u;
      uint32_t g5 = (hi2 < (uint32_t)NW) ? hi2 : 0u;
      uint32_t pos = (p == 0u) ? g0 : (p == 1u) ? g1 : (p == 2u) ? g2v
                   : (p == 3u) ? g3 : (p == 4u) ? g4 : g5;
      uint32_t val = s_base[0][pos];
      uint32_t row = (uint32_t)__shfl((int)val, (int)(base8 + rsrc), 64);
      uint32_t col = (uint32_t)__shfl((int)val, (int)(base8 + csrc), 64);
      bool isbi = (p < 2u) || ((p < 4u) ? (lo2 > 0u) : (hi2 < (uint32_t)NW));
      const float* addr = isbi ? (bigram + (size_t)row * NW + col)
                               : ((p < 4u) ? (startw + col) : (endw + row));
      if (isload) ldA = *addr;
    }
    // prologue B: loads for t=1; vset&1 composes S_0
    {
      uint32_t s0lh = (uint32_t)__builtin_amdgcn_readlane((int)cAlh, 0);
      uint32_t s0sh = (uint32_t)__builtin_amdgcn_readlane((int)cAsh, 0);
      uint32_t s1lh = (uint32_t)__builtin_amdgcn_readlane((int)cAlh, 1);
      uint32_t s1sh = (uint32_t)__builtin_amdgcn_readlane((int)cAsh, 1);
      uint32_t lo2 = s1lh & 0xFFFFu, hi2 = s1lh >> 16, sh2 = s1sh;
      uint32_t g0 = lo2, g1 = lo2 + sh2, g2v = g1 - 1u, g3 = hi2 - 1u;
      uint32_t g4 = (lo2 > 0u) ? lo2 - 1u : 0u;
      uint32_t g5 = (hi2 < (uint32_t)NW) ? hi2 : 0u;
      uint32_t pos = (p == 0u) ? g0 : (p == 1u) ? g1 : (p == 2u) ? g2v
                   : (p == 3u) ? g3 : (p == 4u) ? g4 : g5;
      uint32_t lo0 = s0lh & 0xFFFFu, sp0 = (s0lh >> 16) - lo0, sh0 = s0sh;
      if (vset & 1u) pos = smap2(pos, lo0, sp0, sh0);
      uint32_t val = s_base[0][pos];
      uint32_t row = (uint32_t)__shfl((int)val, (int)(base8 + rsrc), 64);
      uint32_t col = (uint32_t)__shfl((int)val, (int)(base8 + csrc), 64);
      bool isbi = (p < 2u) || ((p < 4u) ? (lo2 > 0u) : (hi2 < (uint32_t)NW));
      const float* addr = isbi ? (bigram + (size_t)row * NW + col)
                               : ((p < 4u) ? (startw + col) : (endw + row));
      if (isload) ldB = *addr;
    }

#define STEPK(K, LD) stepf<K>(lane, sgn, LD, accp, jc, mlh, msh, cAlh, cAsh, cAlg, \
                              sb, s_mvlh, s_mvsh, bigram, startw, endw,            \
                              rsrc, csrc, isload, base8)

    int t = 0;
    for (int b = 0; b < NBOUND; ++b) {
      int wlen = (b < 10) ? 10 : ((b == 10) ? 1 : 11);
      int t_next = t + wlen;

      // prefetch next window's batch (first use ~wlen steps away)
      uint32_t nlh, nsh; float nlg;
      {
        int idx = t_next + (int)(lane < 14u ? lane : 13u);
        if (idx > TSTEPS - 1) idx = TSTEPS - 1;
        if (gprop) { uint4 gp = gprop[idx]; nlh = gp.x; nsh = gp.y; nlg = __uint_as_float(gp.z); }
        else       { make_prop(kchain.a, kchain.b, idx, nlh, nsh, nlg); }
      }

      const uint32_t* sb = s_base[cur];
      STEPK(0, ldA);
      if (wlen > 1) {
        STEPK(1, ldB); STEPK(2, ldA); STEPK(3, ldB); STEPK(4, ldA);
        STEPK(5, ldB); STEPK(6, ldA); STEPK(7, ldB); STEPK(8, ldA); STEPK(9, ldB);
      }
      if (wlen > 10) { STEPK(10, ldA); }

      if (lane == 0u) s_jc[0] = (uint32_t)jc;
      SYNC();                                       // publish move list
      mat_emit(tid, jc, cur, s_mvlh, s_mvsh, s_base, b >= 10, b - 10, out);
      SYNC();                                       // new base complete
      if (wlen & 1) { float tmp = ldA; ldA = ldB; ldB = tmp; }  // loads long done
      cAlh = nlh; cAsh = nsh; cAlg = nlg;
      jc = 0; cur ^= 1u; t = t_next;
    }
#undef STEPK
  } else {
    // ---- waves 1-3: parked; materialize + emit at each boundary ----
    for (int b = 0; b < NBOUND; ++b) {
      SYNC();
      int jcu = __builtin_amdgcn_readfirstlane((int)s_jc[0]);
      mat_emit(tid, jcu, (uint32_t)(b & 1), s_mvlh, s_mvsh, s_base, b >= 10, b - 10, out);
      SYNC();
    }
  }
}

extern "C" void kernel_launch(void* const* d_in, const int* in_sizes, int n_in,
                              void* d_out, int out_size, void* d_ws, size_t ws_size,
                              hipStream_t stream) {
  (void)in_sizes; (void)n_in; (void)out_size;
  const float* bigram = (const float*)d_in[1];
  const float* startw = (const float*)d_in[2];
  const float* endw   = (const float*)d_in[3];
  int* out = (int*)d_out;
  uint4* gprop = nullptr;
  if (ws_size >= (size_t)TSTEPS * 16) {
    gprop = (uint4*)d_ws;
    hipLaunchKernelGGL(prop_kernel, dim3((TSTEPS + 255) / 256), dim3(256), 0, stream, gprop);
  }
  hipLaunchKernelGGL(TwoOptMCMC_86148454023515_kernel, dim3(1), dim3(NTHR), 0, stream,
                     bigram, startw, endw, out, gprop);
}